// Round 9
// baseline (271.401 us; speedup 1.0000x reference)
//
#include <hip/hip_runtime.h>
#include <hip/hip_bf16.h>
#include <cstddef>
#include <cstdint>

#define IN_DIM 512
#define R_DIM 128
#define F_DIM 64
#define H_NUM 4
#define OUT_DIM 64
#define HF 256  // H_NUM * F_DIM

typedef __attribute__((ext_vector_type(4))) float f32x4;
typedef __attribute__((ext_vector_type(8))) short bf16x8;

typedef const __attribute__((address_space(1))) void gas_void;
typedef __attribute__((address_space(3))) void las_void;

__device__ __forceinline__ float bf2f(ushort u) {
    union { uint i; float f; } v; v.i = ((uint)u) << 16; return v.f;
}
__device__ __forceinline__ ushort f2bf(float f) {
    union { float f; uint i; } v; v.f = f;
    uint r = v.i + 0x7fff + ((v.i >> 16) & 1);
    return (ushort)(r >> 16);
}
__device__ __forceinline__ float u2f(uint u) {
    union { uint i; float f; } v; v.i = u; return v.f;
}

// ---------------------------------------------------------------- zero ints
__global__ __launch_bounds__(256) void zero_i32(int* __restrict__ p, int n) {
    int i = blockIdx.x * 256 + threadIdx.x;
    if (i < n) p[i] = 0;
}

// ------------------------------------------------- fold W_seq @ W_lin (heads)
__global__ __launch_bounds__(256) void wcomb1_kernel(const float* __restrict__ Wlin,
                                                     const float* __restrict__ Wseq,
                                                     ushort* __restrict__ Wc) {
    int idx = blockIdx.x * 256 + threadIdx.x;
    if (idx >= H_NUM * F_DIM * IN_DIM) return;
    int i  = idx & (IN_DIM - 1);
    int hf = idx >> 9;          // h*64 + f
    int h  = hf >> 6;
    const float* ws = Wseq + (size_t)hf * R_DIM;
    const float* wl = Wlin + (size_t)h * R_DIM * IN_DIM + i;
    float acc = 0.0f;
#pragma unroll 8
    for (int r = 0; r < R_DIM; ++r) acc += ws[r] * wl[(size_t)r * IN_DIM];
    Wc[idx] = f2bf(acc);
}

// ---------------------------------------------- fold W_seq_c @ W_lin_c (clf)
__global__ __launch_bounds__(256) void wcomb2_kernel(const float* __restrict__ Wlin,
                                                     const float* __restrict__ Wseq,
                                                     ushort* __restrict__ Wc) {
    int idx = blockIdx.x * 256 + threadIdx.x;
    if (idx >= OUT_DIM * HF) return;
    int j = idx & (HF - 1);
    int o = idx >> 8;
    const float* ws = Wseq + (size_t)o * R_DIM;
    const float* wl = Wlin + j;
    float acc = 0.0f;
#pragma unroll 8
    for (int r = 0; r < R_DIM; ++r) acc += ws[r] * wl[(size_t)r * HF];
    Wc[idx] = f2bf(acc);
}

// ----------------------------- bf16 MFMA GEMM TN, fp32 A converted in-flight
// BM=64, BK=64, 256 threads, 2-phase pipelined (double-buffered LDS):
// loop { load A(t+1)->regs; issue B(t+1) gload_lds -> buf^1; compute(buf);
//        cvt+ds_write A(t+1)->buf^1; barrier }  -- one barrier per K-step.
template<int BN, int K, int FS>
__global__ __launch_bounds__(256) void gemm_f32a(const float* __restrict__ A,
                                                 const ushort* __restrict__ B,
                                                 ushort* __restrict__ C,
                                                 int M, int Ntot,
                                                 const float* __restrict__ a1,
                                                 const float* __restrict__ b1,
                                                 const float* __restrict__ a2,
                                                 const float* __restrict__ b2,
                                                 float* __restrict__ f1o,
                                                 float* __restrict__ f2o) {
    constexpr int NF = BN / 16;
    constexpr int HH = BN / 64;
    constexpr int NT = K / 64;
    __shared__ ushort As[2][64 * 64];
    __shared__ ushort Bs[2][BN * 64];
    const int tid = threadIdx.x;
    const int wave = tid >> 6;
    const int lane = tid & 63;
    const int lr = lane & 15;
    const int lg = lane >> 4;
    const int m0 = blockIdx.x * 64;

    int base[2];
#pragma unroll
    for (int ks = 0; ks < 2; ++ks)
        base[ks] = lr * 128 + (((ks * 4 + lg) ^ (lr & 7)) * 16);
    const int abase0 = wave * 2048 + base[0];
    const int abase1 = wave * 2048 + base[1];

    // A staging geometry (constant per thread)
    int s_grow[2], s_ldsoff[2], s_goff[2];
#pragma unroll
    for (int r = 0; r < 2; ++r) {
        int off = r * 4096 + tid * 16;
        int row = off >> 7;
        int lchunk = (off >> 4) & 7;
        int grow = m0 + row;
        if (grow >= M) grow = M - 1;
        s_grow[r] = grow;
        s_goff[r] = lchunk * 8;
        s_ldsoff[r] = row * 128 + ((lchunk ^ (row & 7)) * 16);
    }

    f32x4 acc[NF];
#pragma unroll
    for (int cb = 0; cb < NF; ++cb) acc[cb] = (f32x4)0.0f;

    float4 ar[2][2];

#define ALOAD(K0)                                                          \
    {                                                                      \
        _Pragma("unroll")                                                  \
        for (int r = 0; r < 2; ++r) {                                      \
            const float* g = A + (size_t)s_grow[r] * K + (K0) + s_goff[r]; \
            ar[r][0] = *(const float4*)(g);                                \
            ar[r][1] = *(const float4*)(g + 4);                            \
        }                                                                  \
    }

#define AWRITE(BUF)                                                        \
    {                                                                      \
        _Pragma("unroll")                                                  \
        for (int r = 0; r < 2; ++r) {                                      \
            ushort us[8] = {f2bf(ar[r][0].x), f2bf(ar[r][0].y),            \
                            f2bf(ar[r][0].z), f2bf(ar[r][0].w),            \
                            f2bf(ar[r][1].x), f2bf(ar[r][1].y),            \
                            f2bf(ar[r][1].z), f2bf(ar[r][1].w)};           \
            *(uint4*)((char*)As[BUF] + s_ldsoff[r]) = *(const uint4*)us;   \
        }                                                                  \
    }

#define BSTAGE(BUF, K0)                                                    \
    {                                                                      \
        _Pragma("unroll")                                                  \
        for (int r = 0; r < BN / 32; ++r) {                                \
            int off = r * 4096 + tid * 16;                                 \
            int row = off >> 7;                                            \
            int kch = ((off >> 4) & 7) ^ (row & 7);                        \
            const ushort* g = B + (size_t)row * K + (K0) + kch * 8;        \
            __builtin_amdgcn_global_load_lds((gas_void*)g,                 \
                (las_void*)((char*)Bs[BUF] + off), 16, 0, 0);              \
        }                                                                  \
    }

#define COMPUTE(BUF)                                                       \
    {                                                                      \
        bf16x8 af0 = *(const bf16x8*)((const char*)As[BUF] + abase0);      \
        bf16x8 af1 = *(const bf16x8*)((const char*)As[BUF] + abase1);      \
        _Pragma("unroll")                                                  \
        for (int cg = 0; cg < NF / 4; ++cg) {                              \
            bf16x8 bfr[4];                                                 \
            _Pragma("unroll")                                              \
            for (int j = 0; j < 4; ++j)                                    \
                bfr[j] = *(const bf16x8*)((const char*)Bs[BUF] +           \
                          (cg * 4 + j) * 2048 + base[0]);                  \
            _Pragma("unroll")                                              \
            for (int j = 0; j < 4; ++j)                                    \
                acc[cg * 4 + j] = __builtin_amdgcn_mfma_f32_16x16x32_bf16( \
                    af0, bfr[j], acc[cg * 4 + j], 0, 0, 0);                \
            _Pragma("unroll")                                              \
            for (int j = 0; j < 4; ++j)                                    \
                bfr[j] = *(const bf16x8*)((const char*)Bs[BUF] +           \
                          (cg * 4 + j) * 2048 + base[1]);                  \
            _Pragma("unroll")                                              \
            for (int j = 0; j < 4; ++j)                                    \
                acc[cg * 4 + j] = __builtin_amdgcn_mfma_f32_16x16x32_bf16( \
                    af1, bfr[j], acc[cg * 4 + j], 0, 0, 0);                \
        }                                                                  \
    }

    // prologue: fill buffer 0
    ALOAD(0);
    BSTAGE(0, 0);
    AWRITE(0);          // compiler waits on ar's loads; B drains at barrier
    __syncthreads();

    int buf = 0;
#pragma unroll
    for (int t = 0; t < NT - 1; ++t) {
        ALOAD((t + 1) * 64);       // issue next A (HBM) early
        BSTAGE(buf ^ 1, (t + 1) * 64);  // issue next B (L2) early
        COMPUTE(buf);              // MFMA hides the load latency
        AWRITE(buf ^ 1);
        __syncthreads();           // single drain point per K-step
        buf ^= 1;
    }
    COMPUTE(buf);

#undef ALOAD
#undef AWRITE
#undef BSTAGE
#undef COMPUTE

    // ---- epilogue: C store + fused f1/f2 dots
    float a1v[NF], a2v[NF];
#pragma unroll
    for (int cb = 0; cb < NF; ++cb) {
        int col = cb * 16 + lr;
        a1v[cb] = a1[col];
        a2v[cb] = a2[col];
    }
    const int rowb = m0 + wave * 16 + lg * 4;
#pragma unroll
    for (int r = 0; r < 4; ++r) {
        int row = rowb + r;
        bool ok = row < M;
#pragma unroll
        for (int hh = 0; hh < HH; ++hh) {
            float p1 = 0.f, p2 = 0.f;
#pragma unroll
            for (int c4 = 0; c4 < 4; ++c4) {
                int cb = hh * 4 + c4;
                float v = acc[cb][r];
                p1 += v * a1v[cb];
                p2 += v * a2v[cb];
                if (ok) C[(size_t)row * Ntot + cb * 16 + lr] = f2bf(v);
            }
#pragma unroll
            for (int m = 1; m < 16; m <<= 1) {
                p1 += __shfl_xor(p1, m, 64);
                p2 += __shfl_xor(p2, m, 64);
            }
            if (lr == 0 && ok) {
                f1o[(size_t)row * FS + hh] = p1 + b1[hh];
                f2o[(size_t)row * FS + hh] = p2 + b2[hh];
            }
        }
    }
}

// --------------------------- bf16 MFMA GEMM TN with fused f1/f2 epilogue
// BM=64, 2-phase pipelined, gload_lds both operands, double-buffered LDS.
template<int BN, int K, int FS>
__global__ __launch_bounds__(256) void gemm_bf16(const ushort* __restrict__ A,
                                                 const ushort* __restrict__ B,
                                                 ushort* __restrict__ C,
                                                 int M, int Ntot,
                                                 const float* __restrict__ a1,
                                                 const float* __restrict__ b1,
                                                 const float* __restrict__ a2,
                                                 const float* __restrict__ b2,
                                                 float* __restrict__ f1o,
                                                 float* __restrict__ f2o) {
    constexpr int NF = BN / 16;
    constexpr int HH = BN / 64;
    constexpr int NT = K / 64;
    __shared__ ushort As[2][64 * 64];
    __shared__ ushort Bs[2][BN * 64];
    const int tid = threadIdx.x;
    const int wave = tid >> 6;
    const int lane = tid & 63;
    const int lr = lane & 15;
    const int lg = lane >> 4;
    const int m0 = blockIdx.x * 64;

    int base[2];
#pragma unroll
    for (int ks = 0; ks < 2; ++ks)
        base[ks] = lr * 128 + (((ks * 4 + lg) ^ (lr & 7)) * 16);
    const int abase0 = wave * 2048 + base[0];
    const int abase1 = wave * 2048 + base[1];

    f32x4 acc[NF];
#pragma unroll
    for (int cb = 0; cb < NF; ++cb) acc[cb] = (f32x4)0.0f;

#define STAGE(BUF, K0)                                                     \
    {                                                                      \
        _Pragma("unroll")                                                  \
        for (int r = 0; r < 2; ++r) {                                      \
            int off = r * 4096 + tid * 16;                                 \
            int row = off >> 7;                                            \
            int kch = ((off >> 4) & 7) ^ (row & 7);                        \
            const ushort* g = A + (size_t)(m0 + row) * K + (K0) + kch * 8; \
            __builtin_amdgcn_global_load_lds((gas_void*)g,                 \
                (las_void*)((char*)As[BUF] + off), 16, 0, 0);              \
        }                                                                  \
        _Pragma("unroll")                                                  \
        for (int r = 0; r < BN / 32; ++r) {                                \
            int off = r * 4096 + tid * 16;                                 \
            int row = off >> 7;                                            \
            int kch = ((off >> 4) & 7) ^ (row & 7);                        \
            const ushort* g = B + (size_t)row * K + (K0) + kch * 8;        \
            __builtin_amdgcn_global_load_lds((gas_void*)g,                 \
                (las_void*)((char*)Bs[BUF] + off), 16, 0, 0);              \
        }                                                                  \
    }

#define COMPUTE(BUF)                                                       \
    {                                                                      \
        bf16x8 af0 = *(const bf16x8*)((const char*)As[BUF] + abase0);      \
        bf16x8 af1 = *(const bf16x8*)((const char*)As[BUF] + abase1);      \
        _Pragma("unroll")                                                  \
        for (int cg = 0; cg < NF / 4; ++cg) {                              \
            bf16x8 bfr[4];                                                 \
            _Pragma("unroll")                                              \
            for (int j = 0; j < 4; ++j)                                    \
                bfr[j] = *(const bf16x8*)((const char*)Bs[BUF] +           \
                          (cg * 4 + j) * 2048 + base[0]);                  \
            _Pragma("unroll")                                              \
            for (int j = 0; j < 4; ++j)                                    \
                acc[cg * 4 + j] = __builtin_amdgcn_mfma_f32_16x16x32_bf16( \
                    af0, bfr[j], acc[cg * 4 + j], 0, 0, 0);                \
            _Pragma("unroll")                                              \
            for (int j = 0; j < 4; ++j)                                    \
                bfr[j] = *(const bf16x8*)((const char*)Bs[BUF] +           \
                          (cg * 4 + j) * 2048 + base[1]);                  \
            _Pragma("unroll")                                              \
            for (int j = 0; j < 4; ++j)                                    \
                acc[cg * 4 + j] = __builtin_amdgcn_mfma_f32_16x16x32_bf16( \
                    af1, bfr[j], acc[cg * 4 + j], 0, 0, 0);                \
        }                                                                  \
    }

    STAGE(0, 0);
    __syncthreads();
    int buf = 0;
#pragma unroll
    for (int t = 0; t < NT - 1; ++t) {
        STAGE(buf ^ 1, (t + 1) * 64);   // issue next tile before compute
        COMPUTE(buf);
        __syncthreads();                // drains staged loads (overlapped)
        buf ^= 1;
    }
    COMPUTE(buf);

#undef STAGE
#undef COMPUTE

    float a1v[NF], a2v[NF];
#pragma unroll
    for (int cb = 0; cb < NF; ++cb) {
        int col = cb * 16 + lr;
        a1v[cb] = a1[col];
        a2v[cb] = a2[col];
    }
    const int rowb = m0 + wave * 16 + lg * 4;
#pragma unroll
    for (int r = 0; r < 4; ++r) {
        int row = rowb + r;
        bool ok = row < M;
#pragma unroll
        for (int hh = 0; hh < HH; ++hh) {
            float p1 = 0.f, p2 = 0.f;
#pragma unroll
            for (int c4 = 0; c4 < 4; ++c4) {
                int cb = hh * 4 + c4;
                float v = acc[cb][r];
                p1 += v * a1v[cb];
                p2 += v * a2v[cb];
                if (ok) C[(size_t)row * Ntot + cb * 16 + lr] = f2bf(v);
            }
#pragma unroll
            for (int m = 1; m < 16; m <<= 1) {
                p1 += __shfl_xor(p1, m, 64);
                p2 += __shfl_xor(p2, m, 64);
            }
            if (lr == 0 && ok) {
                f1o[(size_t)row * FS + hh] = p1 + b1[hh];
                f2o[(size_t)row * FS + hh] = p2 + b2[hh];
            }
        }
    }
}

// ------------------------------------------------------------ CSR: histogram
__global__ __launch_bounds__(256) void hist_kernel(const int* __restrict__ src,
                                                   int* __restrict__ counts, int E) {
    int e = blockIdx.x * 256 + threadIdx.x;
    if (e < E) atomicAdd(&counts[src[e]], 1);
}

// ----------------------------------------- scan stage 1: per-block excl scan
__global__ __launch_bounds__(256) void scan_blk(const int* __restrict__ counts,
                                                int* __restrict__ lexcl,
                                                int* __restrict__ part, int N) {
    __shared__ int wsum[4];
    int t = threadIdx.x;
    int g = blockIdx.x * 256 + t;
    int lane = t & 63, wid = t >> 6;
    int v = (g < N) ? counts[g] : 0;
    int x = v;
#pragma unroll
    for (int off = 1; off < 64; off <<= 1) {
        int u = __shfl_up(x, off, 64);
        if (lane >= off) x += u;
    }
    if (lane == 63) wsum[wid] = x;
    __syncthreads();
    int woff = 0;
#pragma unroll
    for (int w = 0; w < 3; ++w) if (w < wid) woff += wsum[w];
    int incl = x + woff;
    if (g < N) lexcl[g] = incl - v;
    if (t == 255) part[blockIdx.x] = incl;
}

// --------------------------------- scan stage 2: excl scan of block partials
__global__ __launch_bounds__(256) void scan_part(int* __restrict__ part, int nb) {
    __shared__ int wsum[4];
    int t = threadIdx.x;
    int lane = t & 63, wid = t >> 6;
    int v = (t < nb) ? part[t] : 0;
    int x = v;
#pragma unroll
    for (int off = 1; off < 64; off <<= 1) {
        int u = __shfl_up(x, off, 64);
        if (lane >= off) x += u;
    }
    if (lane == 63) wsum[wid] = x;
    __syncthreads();
    int woff = 0;
#pragma unroll
    for (int w = 0; w < 3; ++w) if (w < wid) woff += wsum[w];
    int incl = x + woff;
    __syncthreads();
    if (t < nb) part[t] = incl - v;
    if (t == 255) part[nb] = incl;   // grand total
}

// ------------------------------------- scan stage 3: add offsets, emit CSR ptrs
__global__ __launch_bounds__(256) void scan_add(const int* __restrict__ lexcl,
                                                const int* __restrict__ part,
                                                int* __restrict__ starts,
                                                int* __restrict__ cursor, int N, int nb) {
    int g = blockIdx.x * 256 + threadIdx.x;
    if (g < N) {
        int s = lexcl[g] + part[blockIdx.x];
        starts[g] = s;
        cursor[g] = s;
    }
    if (g == 0) starts[N] = part[nb];
}

// ------------------------- CSR: position scatter (writes sorted dst directly)
__global__ __launch_bounds__(256) void scatter_kernel(const int* __restrict__ src,
                                                      const int* __restrict__ dst,
                                                      int* __restrict__ cursor,
                                                      int* __restrict__ dsts, int E) {
    int e = blockIdx.x * 256 + threadIdx.x;
    if (e >= E) return;
    int p = atomicAdd(&cursor[src[e]], 1);
    dsts[p] = dst[e];
}

// ----------------------- gather + normalize + bias + ELU, heads (wave/node)
__global__ __launch_bounds__(256) void gather1_kernel(const int* __restrict__ starts,
                                                      const int* __restrict__ dsts,
                                                      const float* __restrict__ f1,
                                                      const float* __restrict__ f2,
                                                      const ushort* __restrict__ S1,
                                                      const float* __restrict__ bias,
                                                      ushort* __restrict__ hcat, int N) {
    int n = (int)((blockIdx.x * blockDim.x + threadIdx.x) >> 6);
    int lane = threadIdx.x & 63;
    if (n >= N) return;
    const int head = lane >> 4;
    const float f1h = f1[(size_t)n * 4 + head];   // uniform per 16-lane group
    int beg = starts[n], end = starts[n + 1];
    float a0 = 0.f, a1 = 0.f, a2 = 0.f, a3 = 0.f, den = 0.f;
    int i = beg;
    for (; i + 8 <= end; i += 8) {
        int d[8];
        {
            int4 da = *(const int4*)(dsts + i);
            int4 db = *(const int4*)(dsts + i + 4);
            d[0] = da.x; d[1] = da.y; d[2] = da.z; d[3] = da.w;
            d[4] = db.x; d[5] = db.y; d[6] = db.z; d[7] = db.w;
        }
        float g[8];
        uint2 r[8];
#pragma unroll
        for (int j = 0; j < 8; ++j) {
            g[j] = f2[(size_t)d[j] * 4 + head];
            r[j] = *(const uint2*)(S1 + (size_t)d[j] * HF + lane * 4);
        }
#pragma unroll
        for (int j = 0; j < 8; ++j) {
            float l = f1h + g[j]; l = l > 0.f ? l : 0.2f * l;
            float c = __expf(l);
            a0 += c * u2f(r[j].x << 16);
            a1 += c * u2f(r[j].x & 0xffff0000u);
            a2 += c * u2f(r[j].y << 16);
            a3 += c * u2f(r[j].y & 0xffff0000u);
            den += c;
        }
    }
    if (i + 4 <= end) {
        int4 da = *(const int4*)(dsts + i);
        int d[4] = {da.x, da.y, da.z, da.w};
        float g[4];
        uint2 r[4];
#pragma unroll
        for (int j = 0; j < 4; ++j) {
            g[j] = f2[(size_t)d[j] * 4 + head];
            r[j] = *(const uint2*)(S1 + (size_t)d[j] * HF + lane * 4);
        }
#pragma unroll
        for (int j = 0; j < 4; ++j) {
            float l = f1h + g[j]; l = l > 0.f ? l : 0.2f * l;
            float c = __expf(l);
            a0 += c * u2f(r[j].x << 16);
            a1 += c * u2f(r[j].x & 0xffff0000u);
            a2 += c * u2f(r[j].y << 16);
            a3 += c * u2f(r[j].y & 0xffff0000u);
            den += c;
        }
        i += 4;
    }
    for (; i < end; ++i) {
        int d = dsts[i];
        float g = f2[(size_t)d * 4 + head];
        uint2 r = *(const uint2*)(S1 + (size_t)d * HF + lane * 4);
        float l = f1h + g; l = l > 0.f ? l : 0.2f * l;
        float c = __expf(l);
        a0 += c * u2f(r.x << 16);  a1 += c * u2f(r.x & 0xffff0000u);
        a2 += c * u2f(r.y << 16);  a3 += c * u2f(r.y & 0xffff0000u);
        den += c;
    }
    float rd = __builtin_amdgcn_rcpf(den);
    float4 b = *(const float4*)(bias + lane * 4);
    float v0 = a0 * rd + b.x;
    float v1 = a1 * rd + b.y;
    float v2 = a2 * rd + b.z;
    float v3 = a3 * rd + b.w;
    v0 = v0 > 0.f ? v0 : __expf(v0) - 1.f;
    v1 = v1 > 0.f ? v1 : __expf(v1) - 1.f;
    v2 = v2 > 0.f ? v2 : __expf(v2) - 1.f;
    v3 = v3 > 0.f ? v3 : __expf(v3) - 1.f;
    ushort4 o;
    o.x = f2bf(v0); o.y = f2bf(v1); o.z = f2bf(v2); o.w = f2bf(v3);
    *(ushort4*)(hcat + (size_t)n * HF + lane * 4) = o;
}

// --------------------------- gather + normalize + bias, classifier (wave/node)
__global__ __launch_bounds__(256) void gather2_kernel(const int* __restrict__ starts,
                                                      const int* __restrict__ dsts,
                                                      const float* __restrict__ f1,
                                                      const float* __restrict__ f2,
                                                      const ushort* __restrict__ S2,
                                                      const float* __restrict__ bias,
                                                      float* __restrict__ out, int N) {
    int n = (int)((blockIdx.x * blockDim.x + threadIdx.x) >> 6);
    int lane = threadIdx.x & 63;
    if (n >= N) return;
    const float f1u = f1[n];
    int beg = starts[n], end = starts[n + 1];
    float acc = 0.f, den = 0.f;
    int i = beg;
    for (; i + 8 <= end; i += 8) {
        int d[8];
        {
            int4 da = *(const int4*)(dsts + i);
            int4 db = *(const int4*)(dsts + i + 4);
            d[0] = da.x; d[1] = da.y; d[2] = da.z; d[3] = da.w;
            d[4] = db.x; d[5] = db.y; d[6] = db.z; d[7] = db.w;
        }
        float g[8];
        ushort r[8];
#pragma unroll
        for (int j = 0; j < 8; ++j) {
            g[j] = f2[d[j]];
            r[j] = S2[(size_t)d[j] * OUT_DIM + lane];
        }
#pragma unroll
        for (int j = 0; j < 8; ++j) {
            float l = f1u + g[j]; l = l > 0.f ? l : 0.2f * l;
            float c = __expf(l);
            acc += c * bf2f(r[j]);
            den += c;
        }
    }
    if (i + 4 <= end) {
        int4 da = *(const int4*)(dsts + i);
        int d[4] = {da.x, da.y, da.z, da.w};
        float g[4];
        ushort r[4];
#pragma unroll
        for (int j = 0; j < 4; ++j) {
            g[j] = f2[d[j]];
            r[j] = S2[(size_t)d[j] * OUT_DIM + lane];
        }
#pragma unroll
        for (int j = 0; j < 4; ++j) {
            float l = f1u + g[j]; l = l > 0.f ? l : 0.2f * l;
            float c = __expf(l);
            acc += c * bf2f(r[j]);
            den += c;
        }
        i += 4;
    }
    for (; i < end; ++i) {
        int d = dsts[i];
        float l = f1u + f2[d]; l = l > 0.f ? l : 0.2f * l;
        float c = __expf(l);
        acc += c * bf2f(S2[(size_t)d * OUT_DIM + lane]);
        den += c;
    }
    out[(size_t)n * OUT_DIM + lane] = acc * __builtin_amdgcn_rcpf(den) + bias[lane];
}

// ===========================================================================
extern "C" void kernel_launch(void* const* d_in, const int* in_sizes, int n_in,
                              void* d_out, int out_size, void* d_ws, size_t ws_size,
                              hipStream_t stream) {
    const float* x      = (const float*)d_in[0];
    const int*   edges  = (const int*)d_in[1];
    const float* Wlin_h = (const float*)d_in[2];
    const float* Wseq_h = (const float*)d_in[3];
    const float* a1_h   = (const float*)d_in[4];
    const float* b1_h   = (const float*)d_in[5];
    const float* a2_h   = (const float*)d_in[6];
    const float* b2_h   = (const float*)d_in[7];
    const float* bias_h = (const float*)d_in[8];
    const float* Wlin_c = (const float*)d_in[9];
    const float* Wseq_c = (const float*)d_in[10];
    const float* a1_c   = (const float*)d_in[11];
    const float* b1_c   = (const float*)d_in[12];
    const float* a2_c   = (const float*)d_in[13];
    const float* b2_c   = (const float*)d_in[14];
    const float* bias_c = (const float*)d_in[15];

    const int N = in_sizes[0] / IN_DIM;
    const int E = in_sizes[1] / 2;
    const int* src = edges;
    const int* dst = edges + E;

    char* ws = (char*)d_ws;
    size_t off = 0;
    ushort* WC1   = (ushort*)(ws + off); off += (size_t)HF * IN_DIM * 2;
    ushort* WC2   = (ushort*)(ws + off); off += (size_t)OUT_DIM * HF * 2;
    ushort* S1    = (ushort*)(ws + off); off += (size_t)N * HF * 2;
    ushort* S2    = S1;  // S1 dead after gather1; reuse for S2 [N][64]
    ushort* HCAT  = (ushort*)(ws + off); off += (size_t)N * HF * 2;
    float*  F1    = (float*)(ws + off);  off += (size_t)N * H_NUM * 4;
    float*  F2    = (float*)(ws + off);  off += (size_t)N * H_NUM * 4;
    float*  F1c   = (float*)(ws + off);  off += (size_t)N * 4;
    float*  F2c   = (float*)(ws + off);  off += (size_t)N * 4;
    int* COUNTS   = (int*)(ws + off);    off += (size_t)N * 4;
    int* STARTS   = (int*)(ws + off);    off += ((size_t)N + 1) * 4;
    int* CURSOR   = (int*)(ws + off);    off += (size_t)N * 4;
    int* DSTS     = (int*)(ws + off);    off += (size_t)E * 4;
    int* LEXCL    = (int*)(ws + off);    off += (size_t)N * 4;
    int* PART     = (int*)(ws + off);    off += 512 * 4;

    float* out = (float*)d_out;

    const int eg = (E + 255) / 256;
    const int NB = (N + 255) / 256;

    // ---- CSR build (shared by both layers); DSTS = dst sorted by src
    hipLaunchKernelGGL(zero_i32, dim3(NB), dim3(256), 0, stream, COUNTS, N);
    hipLaunchKernelGGL(hist_kernel, dim3(eg), dim3(256), 0, stream, src, COUNTS, E);
    hipLaunchKernelGGL(scan_blk, dim3(NB), dim3(256), 0, stream, COUNTS, LEXCL, PART, N);
    hipLaunchKernelGGL(scan_part, dim3(1), dim3(256), 0, stream, PART, NB);
    hipLaunchKernelGGL(scan_add, dim3(NB), dim3(256), 0, stream, LEXCL, PART, STARTS, CURSOR, N, NB);
    hipLaunchKernelGGL(scatter_kernel, dim3(eg), dim3(256), 0, stream, src, dst, CURSOR, DSTS, E);

    // ---- fold weights (bf16 out)
    hipLaunchKernelGGL(wcomb1_kernel, dim3((HF * IN_DIM + 255) / 256), dim3(256),
                       0, stream, Wlin_h, Wseq_h, WC1);
    hipLaunchKernelGGL(wcomb2_kernel, dim3((OUT_DIM * HF + 255) / 256), dim3(256),
                       0, stream, Wlin_c, Wseq_c, WC2);

    // ---- layer 1: S1 = x @ Wc1^T  (BM=64; pipelined; fused f1/f2 heads)
    hipLaunchKernelGGL((gemm_f32a<HF, IN_DIM, 4>), dim3((N + 63) / 64, 1), dim3(256),
                       0, stream, x, WC1, S1, N, HF,
                       a1_h, b1_h, a2_h, b2_h, F1, F2);

    // ---- gather layer 1 (inline coef + normalize + bias + ELU) -> HCAT bf16
    hipLaunchKernelGGL(gather1_kernel, dim3((N + 3) / 4), dim3(256), 0, stream,
                       STARTS, DSTS, F1, F2, S1, bias_h, HCAT, N);

    // ---- classifier: S2 = hcat @ Wc2^T  (BM=64; pipelined; fused f1c/f2c)
    hipLaunchKernelGGL((gemm_bf16<OUT_DIM, HF, 1>), dim3((N + 63) / 64, 1), dim3(256),
                       0, stream, HCAT, WC2, S2, N, OUT_DIM,
                       a1_c, b1_c, a2_c, b2_c, F1c, F2c);

    // ---- gather classifier (inline coef + normalize + bias) -> out fp32
    hipLaunchKernelGGL(gather2_kernel, dim3((N + 3) / 4), dim3(256), 0, stream,
                       STARTS, DSTS, F1c, F2c, S2, bias_c, out, N);
}

// Round 10
// 262.019 us; speedup vs baseline: 1.0358x; 1.0358x over previous
//
#include <hip/hip_runtime.h>
#include <hip/hip_bf16.h>
#include <cstddef>
#include <cstdint>

#define IN_DIM 512
#define R_DIM 128
#define F_DIM 64
#define H_NUM 4
#define OUT_DIM 64
#define HF 256  // H_NUM * F_DIM

typedef __attribute__((ext_vector_type(4))) float f32x4;
typedef __attribute__((ext_vector_type(8))) short bf16x8;

typedef const __attribute__((address_space(1))) void gas_void;
typedef __attribute__((address_space(3))) void las_void;

__device__ __forceinline__ float bf2f(ushort u) {
    union { uint i; float f; } v; v.i = ((uint)u) << 16; return v.f;
}
__device__ __forceinline__ ushort f2bf(float f) {
    union { float f; uint i; } v; v.f = f;
    uint r = v.i + 0x7fff + ((v.i >> 16) & 1);
    return (ushort)(r >> 16);
}
__device__ __forceinline__ float u2f(uint u) {
    union { uint i; float f; } v; v.i = u; return v.f;
}

// ---------------------------------------------------------------- zero ints
__global__ __launch_bounds__(256) void zero_i32(int* __restrict__ p, int n) {
    int i = blockIdx.x * 256 + threadIdx.x;
    if (i < n) p[i] = 0;
}

// ------------------------------------------------- fold W_seq @ W_lin (heads)
__global__ __launch_bounds__(256) void wcomb1_kernel(const float* __restrict__ Wlin,
                                                     const float* __restrict__ Wseq,
                                                     ushort* __restrict__ Wc) {
    int idx = blockIdx.x * 256 + threadIdx.x;
    if (idx >= H_NUM * F_DIM * IN_DIM) return;
    int i  = idx & (IN_DIM - 1);
    int hf = idx >> 9;          // h*64 + f
    int h  = hf >> 6;
    const float* ws = Wseq + (size_t)hf * R_DIM;
    const float* wl = Wlin + (size_t)h * R_DIM * IN_DIM + i;
    float acc = 0.0f;
#pragma unroll 8
    for (int r = 0; r < R_DIM; ++r) acc += ws[r] * wl[(size_t)r * IN_DIM];
    Wc[idx] = f2bf(acc);
}

// ---------------------------------------------- fold W_seq_c @ W_lin_c (clf)
__global__ __launch_bounds__(256) void wcomb2_kernel(const float* __restrict__ Wlin,
                                                     const float* __restrict__ Wseq,
                                                     ushort* __restrict__ Wc) {
    int idx = blockIdx.x * 256 + threadIdx.x;
    if (idx >= OUT_DIM * HF) return;
    int j = idx & (HF - 1);
    int o = idx >> 8;
    const float* ws = Wseq + (size_t)o * R_DIM;
    const float* wl = Wlin + j;
    float acc = 0.0f;
#pragma unroll 8
    for (int r = 0; r < R_DIM; ++r) acc += ws[r] * wl[(size_t)r * HF];
    Wc[idx] = f2bf(acc);
}

// ----------------------------- bf16 MFMA GEMM TN, fp32 A converted in-flight
// BM=64, BN=128 (grid.y column split), BK=64, 256 threads, single-buffer LDS
// (24 KB -> ~6 blocks/CU). Fused f1/f2 attention-dot epilogue for this
// block's 2-head slice.
template<int BN, int K, int FS>
__global__ __launch_bounds__(256) void gemm_f32a(const float* __restrict__ A,
                                                 const ushort* __restrict__ B,
                                                 ushort* __restrict__ C,
                                                 int M, int Ntot,
                                                 const float* __restrict__ a1,
                                                 const float* __restrict__ b1,
                                                 const float* __restrict__ a2,
                                                 const float* __restrict__ b2,
                                                 float* __restrict__ f1o,
                                                 float* __restrict__ f2o) {
    constexpr int NF = BN / 16;
    constexpr int HH = BN / 64;
    __shared__ ushort As[64 * 64];
    __shared__ ushort Bs[BN * 64];
    const int tid = threadIdx.x;
    const int wave = tid >> 6;
    const int lane = tid & 63;
    const int lr = lane & 15;
    const int lg = lane >> 4;
    const int m0 = blockIdx.x * 64;
    const int n0 = blockIdx.y * BN;
    const int h0 = blockIdx.y * HH;

    int base[2];
#pragma unroll
    for (int ks = 0; ks < 2; ++ks)
        base[ks] = lr * 128 + (((ks * 4 + lg) ^ (lr & 7)) * 16);
    const int abase0 = wave * 2048 + base[0];
    const int abase1 = wave * 2048 + base[1];

    // A staging geometry (constant per thread)
    int s_grow[2], s_ldsoff[2], s_goff[2];
#pragma unroll
    for (int r = 0; r < 2; ++r) {
        int off = r * 4096 + tid * 16;
        int row = off >> 7;
        int lchunk = (off >> 4) & 7;
        int grow = m0 + row;
        if (grow >= M) grow = M - 1;
        s_grow[r] = grow;
        s_goff[r] = lchunk * 8;
        s_ldsoff[r] = row * 128 + ((lchunk ^ (row & 7)) * 16);
    }

    f32x4 acc[NF];
#pragma unroll
    for (int cb = 0; cb < NF; ++cb) acc[cb] = (f32x4)0.0f;

    for (int k0 = 0; k0 < K; k0 += 64) {
        // ---- stage B via global_load_lds (pre-swizzled source)
#pragma unroll
        for (int r = 0; r < BN / 32; ++r) {
            int off = r * 4096 + tid * 16;
            int row = off >> 7;
            int kch = ((off >> 4) & 7) ^ (row & 7);
            const ushort* g = B + (size_t)(n0 + row) * K + k0 + kch * 8;
            __builtin_amdgcn_global_load_lds((gas_void*)g,
                                             (las_void*)((char*)Bs + off), 16, 0, 0);
        }
        // ---- stage A: fp32 load -> bf16 cvt -> swizzled ds_write
#pragma unroll
        for (int r = 0; r < 2; ++r) {
            const float* g = A + (size_t)s_grow[r] * K + k0 + s_goff[r];
            float4 v0 = *(const float4*)(g);
            float4 v1 = *(const float4*)(g + 4);
            ushort us[8] = {f2bf(v0.x), f2bf(v0.y), f2bf(v0.z), f2bf(v0.w),
                            f2bf(v1.x), f2bf(v1.y), f2bf(v1.z), f2bf(v1.w)};
            *(uint4*)((char*)As + s_ldsoff[r]) = *(const uint4*)us;
        }
        __syncthreads();
        {
            bf16x8 af0 = *(const bf16x8*)((const char*)As + abase0);
            bf16x8 af1 = *(const bf16x8*)((const char*)As + abase1);
#pragma unroll
            for (int cg = 0; cg < NF / 4; ++cg) {
                bf16x8 bfr[4];
#pragma unroll
                for (int j = 0; j < 4; ++j)
                    bfr[j] = *(const bf16x8*)((const char*)Bs + (cg * 4 + j) * 2048 + base[0]);
#pragma unroll
                for (int j = 0; j < 4; ++j)
                    acc[cg * 4 + j] = __builtin_amdgcn_mfma_f32_16x16x32_bf16(
                        af0, bfr[j], acc[cg * 4 + j], 0, 0, 0);
#pragma unroll
                for (int j = 0; j < 4; ++j)
                    bfr[j] = *(const bf16x8*)((const char*)Bs + (cg * 4 + j) * 2048 + base[1]);
#pragma unroll
                for (int j = 0; j < 4; ++j)
                    acc[cg * 4 + j] = __builtin_amdgcn_mfma_f32_16x16x32_bf16(
                        af1, bfr[j], acc[cg * 4 + j], 0, 0, 0);
            }
        }
        __syncthreads();
    }

    // ---- epilogue: C store + fused f1/f2 dots for this block's heads
    float a1v[NF], a2v[NF];
#pragma unroll
    for (int cb = 0; cb < NF; ++cb) {
        int col = n0 + cb * 16 + lr;
        a1v[cb] = a1[col];
        a2v[cb] = a2[col];
    }
    const int rowb = m0 + wave * 16 + lg * 4;
#pragma unroll
    for (int r = 0; r < 4; ++r) {
        int row = rowb + r;
        bool ok = row < M;
#pragma unroll
        for (int hh = 0; hh < HH; ++hh) {
            float p1 = 0.f, p2 = 0.f;
#pragma unroll
            for (int c4 = 0; c4 < 4; ++c4) {
                int cb = hh * 4 + c4;
                float v = acc[cb][r];
                p1 += v * a1v[cb];
                p2 += v * a2v[cb];
                if (ok) C[(size_t)row * Ntot + n0 + cb * 16 + lr] = f2bf(v);
            }
#pragma unroll
            for (int m = 1; m < 16; m <<= 1) {
                p1 += __shfl_xor(p1, m, 64);
                p2 += __shfl_xor(p2, m, 64);
            }
            if (lr == 0 && ok) {
                f1o[(size_t)row * FS + h0 + hh] = p1 + b1[h0 + hh];
                f2o[(size_t)row * FS + h0 + hh] = p2 + b2[h0 + hh];
            }
        }
    }
}

// --------------------------- bf16 MFMA GEMM TN with fused f1/f2 epilogue
// BM=64, single-buffer LDS (16 KB), gload_lds both operands.
template<int BN, int K, int FS>
__global__ __launch_bounds__(256) void gemm_bf16(const ushort* __restrict__ A,
                                                 const ushort* __restrict__ B,
                                                 ushort* __restrict__ C,
                                                 int M, int Ntot,
                                                 const float* __restrict__ a1,
                                                 const float* __restrict__ b1,
                                                 const float* __restrict__ a2,
                                                 const float* __restrict__ b2,
                                                 float* __restrict__ f1o,
                                                 float* __restrict__ f2o) {
    constexpr int NF = BN / 16;
    constexpr int HH = BN / 64;
    __shared__ ushort As[64 * 64];
    __shared__ ushort Bs[BN * 64];
    const int tid = threadIdx.x;
    const int wave = tid >> 6;
    const int lane = tid & 63;
    const int lr = lane & 15;
    const int lg = lane >> 4;
    const int m0 = blockIdx.x * 64;

    int base[2];
#pragma unroll
    for (int ks = 0; ks < 2; ++ks)
        base[ks] = lr * 128 + (((ks * 4 + lg) ^ (lr & 7)) * 16);
    const int abase0 = wave * 2048 + base[0];
    const int abase1 = wave * 2048 + base[1];

    f32x4 acc[NF];
#pragma unroll
    for (int cb = 0; cb < NF; ++cb) acc[cb] = (f32x4)0.0f;

    for (int k0 = 0; k0 < K; k0 += 64) {
#pragma unroll
        for (int r = 0; r < 2; ++r) {
            int off = r * 4096 + tid * 16;
            int row = off >> 7;
            int kch = ((off >> 4) & 7) ^ (row & 7);
            const ushort* g = A + (size_t)(m0 + row) * K + k0 + kch * 8;
            __builtin_amdgcn_global_load_lds((gas_void*)g,
                                             (las_void*)((char*)As + off), 16, 0, 0);
        }
#pragma unroll
        for (int r = 0; r < BN / 32; ++r) {
            int off = r * 4096 + tid * 16;
            int row = off >> 7;
            int kch = ((off >> 4) & 7) ^ (row & 7);
            const ushort* g = B + (size_t)row * K + k0 + kch * 8;
            __builtin_amdgcn_global_load_lds((gas_void*)g,
                                             (las_void*)((char*)Bs + off), 16, 0, 0);
        }
        __syncthreads();
        {
            bf16x8 af0 = *(const bf16x8*)((const char*)As + abase0);
            bf16x8 af1 = *(const bf16x8*)((const char*)As + abase1);
#pragma unroll
            for (int cg = 0; cg < NF / 4; ++cg) {
                bf16x8 bfr[4];
#pragma unroll
                for (int j = 0; j < 4; ++j)
                    bfr[j] = *(const bf16x8*)((const char*)Bs + (cg * 4 + j) * 2048 + base[0]);
#pragma unroll
                for (int j = 0; j < 4; ++j)
                    acc[cg * 4 + j] = __builtin_amdgcn_mfma_f32_16x16x32_bf16(
                        af0, bfr[j], acc[cg * 4 + j], 0, 0, 0);
#pragma unroll
                for (int j = 0; j < 4; ++j)
                    bfr[j] = *(const bf16x8*)((const char*)Bs + (cg * 4 + j) * 2048 + base[1]);
#pragma unroll
                for (int j = 0; j < 4; ++j)
                    acc[cg * 4 + j] = __builtin_amdgcn_mfma_f32_16x16x32_bf16(
                        af1, bfr[j], acc[cg * 4 + j], 0, 0, 0);
            }
        }
        __syncthreads();
    }

    float a1v[NF], a2v[NF];
#pragma unroll
    for (int cb = 0; cb < NF; ++cb) {
        int col = cb * 16 + lr;
        a1v[cb] = a1[col];
        a2v[cb] = a2[col];
    }
    const int rowb = m0 + wave * 16 + lg * 4;
#pragma unroll
    for (int r = 0; r < 4; ++r) {
        int row = rowb + r;
        bool ok = row < M;
#pragma unroll
        for (int hh = 0; hh < HH; ++hh) {
            float p1 = 0.f, p2 = 0.f;
#pragma unroll
            for (int c4 = 0; c4 < 4; ++c4) {
                int cb = hh * 4 + c4;
                float v = acc[cb][r];
                p1 += v * a1v[cb];
                p2 += v * a2v[cb];
                if (ok) C[(size_t)row * Ntot + cb * 16 + lr] = f2bf(v);
            }
#pragma unroll
            for (int m = 1; m < 16; m <<= 1) {
                p1 += __shfl_xor(p1, m, 64);
                p2 += __shfl_xor(p2, m, 64);
            }
            if (lr == 0 && ok) {
                f1o[(size_t)row * FS + hh] = p1 + b1[hh];
                f2o[(size_t)row * FS + hh] = p2 + b2[hh];
            }
        }
    }
}

// ------------------------------------------------------------ CSR: histogram
__global__ __launch_bounds__(256) void hist_kernel(const int* __restrict__ src,
                                                   int* __restrict__ counts, int E) {
    int e = blockIdx.x * 256 + threadIdx.x;
    if (e < E) atomicAdd(&counts[src[e]], 1);
}

// ----------------------------------------- scan stage 1: per-block excl scan
__global__ __launch_bounds__(256) void scan_blk(const int* __restrict__ counts,
                                                int* __restrict__ lexcl,
                                                int* __restrict__ part, int N) {
    __shared__ int wsum[4];
    int t = threadIdx.x;
    int g = blockIdx.x * 256 + t;
    int lane = t & 63, wid = t >> 6;
    int v = (g < N) ? counts[g] : 0;
    int x = v;
#pragma unroll
    for (int off = 1; off < 64; off <<= 1) {
        int u = __shfl_up(x, off, 64);
        if (lane >= off) x += u;
    }
    if (lane == 63) wsum[wid] = x;
    __syncthreads();
    int woff = 0;
#pragma unroll
    for (int w = 0; w < 3; ++w) if (w < wid) woff += wsum[w];
    int incl = x + woff;
    if (g < N) lexcl[g] = incl - v;
    if (t == 255) part[blockIdx.x] = incl;
}

// --------------------------------- scan stage 2: excl scan of block partials
__global__ __launch_bounds__(256) void scan_part(int* __restrict__ part, int nb) {
    __shared__ int wsum[4];
    int t = threadIdx.x;
    int lane = t & 63, wid = t >> 6;
    int v = (t < nb) ? part[t] : 0;
    int x = v;
#pragma unroll
    for (int off = 1; off < 64; off <<= 1) {
        int u = __shfl_up(x, off, 64);
        if (lane >= off) x += u;
    }
    if (lane == 63) wsum[wid] = x;
    __syncthreads();
    int woff = 0;
#pragma unroll
    for (int w = 0; w < 3; ++w) if (w < wid) woff += wsum[w];
    int incl = x + woff;
    __syncthreads();
    if (t < nb) part[t] = incl - v;
    if (t == 255) part[nb] = incl;   // grand total
}

// ------------------------------------- scan stage 3: add offsets, emit CSR ptrs
__global__ __launch_bounds__(256) void scan_add(const int* __restrict__ lexcl,
                                                const int* __restrict__ part,
                                                int* __restrict__ starts,
                                                int* __restrict__ cursor, int N, int nb) {
    int g = blockIdx.x * 256 + threadIdx.x;
    if (g < N) {
        int s = lexcl[g] + part[blockIdx.x];
        starts[g] = s;
        cursor[g] = s;
    }
    if (g == 0) starts[N] = part[nb];
}

// ------------------------- CSR: position scatter (writes sorted dst directly)
__global__ __launch_bounds__(256) void scatter_kernel(const int* __restrict__ src,
                                                      const int* __restrict__ dst,
                                                      int* __restrict__ cursor,
                                                      int* __restrict__ dsts, int E) {
    int e = blockIdx.x * 256 + threadIdx.x;
    if (e >= E) return;
    int p = atomicAdd(&cursor[src[e]], 1);
    dsts[p] = dst[e];
}

// ----------------------- gather + normalize + bias + ELU, heads (wave/node)
__global__ __launch_bounds__(256) void gather1_kernel(const int* __restrict__ starts,
                                                      const int* __restrict__ dsts,
                                                      const float* __restrict__ f1,
                                                      const float* __restrict__ f2,
                                                      const ushort* __restrict__ S1,
                                                      const float* __restrict__ bias,
                                                      ushort* __restrict__ hcat, int N) {
    int n = (int)((blockIdx.x * blockDim.x + threadIdx.x) >> 6);
    int lane = threadIdx.x & 63;
    if (n >= N) return;
    const int head = lane >> 4;
    const float f1h = f1[(size_t)n * 4 + head];   // uniform per 16-lane group
    int beg = starts[n], end = starts[n + 1];
    float a0 = 0.f, a1 = 0.f, a2 = 0.f, a3 = 0.f, den = 0.f;
    int i = beg;
    for (; i + 8 <= end; i += 8) {
        int d[8];
        {
            int4 da = *(const int4*)(dsts + i);
            int4 db = *(const int4*)(dsts + i + 4);
            d[0] = da.x; d[1] = da.y; d[2] = da.z; d[3] = da.w;
            d[4] = db.x; d[5] = db.y; d[6] = db.z; d[7] = db.w;
        }
        float g[8];
        uint2 r[8];
#pragma unroll
        for (int j = 0; j < 8; ++j) {
            g[j] = f2[(size_t)d[j] * 4 + head];
            r[j] = *(const uint2*)(S1 + (size_t)d[j] * HF + lane * 4);
        }
#pragma unroll
        for (int j = 0; j < 8; ++j) {
            float l = f1h + g[j]; l = l > 0.f ? l : 0.2f * l;
            float c = __expf(l);
            a0 += c * u2f(r[j].x << 16);
            a1 += c * u2f(r[j].x & 0xffff0000u);
            a2 += c * u2f(r[j].y << 16);
            a3 += c * u2f(r[j].y & 0xffff0000u);
            den += c;
        }
    }
    if (i + 4 <= end) {
        int4 da = *(const int4*)(dsts + i);
        int d[4] = {da.x, da.y, da.z, da.w};
        float g[4];
        uint2 r[4];
#pragma unroll
        for (int j = 0; j < 4; ++j) {
            g[j] = f2[(size_t)d[j] * 4 + head];
            r[j] = *(const uint2*)(S1 + (size_t)d[j] * HF + lane * 4);
        }
#pragma unroll
        for (int j = 0; j < 4; ++j) {
            float l = f1h + g[j]; l = l > 0.f ? l : 0.2f * l;
            float c = __expf(l);
            a0 += c * u2f(r[j].x << 16);
            a1 += c * u2f(r[j].x & 0xffff0000u);
            a2 += c * u2f(r[j].y << 16);
            a3 += c * u2f(r[j].y & 0xffff0000u);
            den += c;
        }
        i += 4;
    }
    for (; i < end; ++i) {
        int d = dsts[i];
        float g = f2[(size_t)d * 4 + head];
        uint2 r = *(const uint2*)(S1 + (size_t)d * HF + lane * 4);
        float l = f1h + g; l = l > 0.f ? l : 0.2f * l;
        float c = __expf(l);
        a0 += c * u2f(r.x << 16);  a1 += c * u2f(r.x & 0xffff0000u);
        a2 += c * u2f(r.y << 16);  a3 += c * u2f(r.y & 0xffff0000u);
        den += c;
    }
    float rd = __builtin_amdgcn_rcpf(den);
    float4 b = *(const float4*)(bias + lane * 4);
    float v0 = a0 * rd + b.x;
    float v1 = a1 * rd + b.y;
    float v2 = a2 * rd + b.z;
    float v3 = a3 * rd + b.w;
    v0 = v0 > 0.f ? v0 : __expf(v0) - 1.f;
    v1 = v1 > 0.f ? v1 : __expf(v1) - 1.f;
    v2 = v2 > 0.f ? v2 : __expf(v2) - 1.f;
    v3 = v3 > 0.f ? v3 : __expf(v3) - 1.f;
    ushort4 o;
    o.x = f2bf(v0); o.y = f2bf(v1); o.z = f2bf(v2); o.w = f2bf(v3);
    *(ushort4*)(hcat + (size_t)n * HF + lane * 4) = o;
}

// --------------------------- gather + normalize + bias, classifier (wave/node)
__global__ __launch_bounds__(256) void gather2_kernel(const int* __restrict__ starts,
                                                      const int* __restrict__ dsts,
                                                      const float* __restrict__ f1,
                                                      const float* __restrict__ f2,
                                                      const ushort* __restrict__ S2,
                                                      const float* __restrict__ bias,
                                                      float* __restrict__ out, int N) {
    int n = (int)((blockIdx.x * blockDim.x + threadIdx.x) >> 6);
    int lane = threadIdx.x & 63;
    if (n >= N) return;
    const float f1u = f1[n];
    int beg = starts[n], end = starts[n + 1];
    float acc = 0.f, den = 0.f;
    int i = beg;
    for (; i + 8 <= end; i += 8) {
        int d[8];
        {
            int4 da = *(const int4*)(dsts + i);
            int4 db = *(const int4*)(dsts + i + 4);
            d[0] = da.x; d[1] = da.y; d[2] = da.z; d[3] = da.w;
            d[4] = db.x; d[5] = db.y; d[6] = db.z; d[7] = db.w;
        }
        float g[8];
        ushort r[8];
#pragma unroll
        for (int j = 0; j < 8; ++j) {
            g[j] = f2[d[j]];
            r[j] = S2[(size_t)d[j] * OUT_DIM + lane];
        }
#pragma unroll
        for (int j = 0; j < 8; ++j) {
            float l = f1u + g[j]; l = l > 0.f ? l : 0.2f * l;
            float c = __expf(l);
            acc += c * bf2f(r[j]);
            den += c;
        }
    }
    if (i + 4 <= end) {
        int4 da = *(const int4*)(dsts + i);
        int d[4] = {da.x, da.y, da.z, da.w};
        float g[4];
        ushort r[4];
#pragma unroll
        for (int j = 0; j < 4; ++j) {
            g[j] = f2[d[j]];
            r[j] = S2[(size_t)d[j] * OUT_DIM + lane];
        }
#pragma unroll
        for (int j = 0; j < 4; ++j) {
            float l = f1u + g[j]; l = l > 0.f ? l : 0.2f * l;
            float c = __expf(l);
            acc += c * bf2f(r[j]);
            den += c;
        }
        i += 4;
    }
    for (; i < end; ++i) {
        int d = dsts[i];
        float l = f1u + f2[d]; l = l > 0.f ? l : 0.2f * l;
        float c = __expf(l);
        acc += c * bf2f(S2[(size_t)d * OUT_DIM + lane]);
        den += c;
    }
    out[(size_t)n * OUT_DIM + lane] = acc * __builtin_amdgcn_rcpf(den) + bias[lane];
}

// ===========================================================================
extern "C" void kernel_launch(void* const* d_in, const int* in_sizes, int n_in,
                              void* d_out, int out_size, void* d_ws, size_t ws_size,
                              hipStream_t stream) {
    const float* x      = (const float*)d_in[0];
    const int*   edges  = (const int*)d_in[1];
    const float* Wlin_h = (const float*)d_in[2];
    const float* Wseq_h = (const float*)d_in[3];
    const float* a1_h   = (const float*)d_in[4];
    const float* b1_h   = (const float*)d_in[5];
    const float* a2_h   = (const float*)d_in[6];
    const float* b2_h   = (const float*)d_in[7];
    const float* bias_h = (const float*)d_in[8];
    const float* Wlin_c = (const float*)d_in[9];
    const float* Wseq_c = (const float*)d_in[10];
    const float* a1_c   = (const float*)d_in[11];
    const float* b1_c   = (const float*)d_in[12];
    const float* a2_c   = (const float*)d_in[13];
    const float* b2_c   = (const float*)d_in[14];
    const float* bias_c = (const float*)d_in[15];

    const int N = in_sizes[0] / IN_DIM;
    const int E = in_sizes[1] / 2;
    const int* src = edges;
    const int* dst = edges + E;

    char* ws = (char*)d_ws;
    size_t off = 0;
    ushort* WC1   = (ushort*)(ws + off); off += (size_t)HF * IN_DIM * 2;
    ushort* WC2   = (ushort*)(ws + off); off += (size_t)OUT_DIM * HF * 2;
    ushort* S1    = (ushort*)(ws + off); off += (size_t)N * HF * 2;
    ushort* S2    = S1;  // S1 dead after gather1; reuse for S2 [N][64]
    ushort* HCAT  = (ushort*)(ws + off); off += (size_t)N * HF * 2;
    float*  F1    = (float*)(ws + off);  off += (size_t)N * H_NUM * 4;
    float*  F2    = (float*)(ws + off);  off += (size_t)N * H_NUM * 4;
    float*  F1c   = (float*)(ws + off);  off += (size_t)N * 4;
    float*  F2c   = (float*)(ws + off);  off += (size_t)N * 4;
    int* COUNTS   = (int*)(ws + off);    off += (size_t)N * 4;
    int* STARTS   = (int*)(ws + off);    off += ((size_t)N + 1) * 4;
    int* CURSOR   = (int*)(ws + off);    off += (size_t)N * 4;
    int* DSTS     = (int*)(ws + off);    off += (size_t)E * 4;
    int* LEXCL    = (int*)(ws + off);    off += (size_t)N * 4;
    int* PART     = (int*)(ws + off);    off += 512 * 4;

    float* out = (float*)d_out;

    const int eg = (E + 255) / 256;
    const int NB = (N + 255) / 256;

    // ---- CSR build (shared by both layers); DSTS = dst sorted by src
    hipLaunchKernelGGL(zero_i32, dim3(NB), dim3(256), 0, stream, COUNTS, N);
    hipLaunchKernelGGL(hist_kernel, dim3(eg), dim3(256), 0, stream, src, COUNTS, E);
    hipLaunchKernelGGL(scan_blk, dim3(NB), dim3(256), 0, stream, COUNTS, LEXCL, PART, N);
    hipLaunchKernelGGL(scan_part, dim3(1), dim3(256), 0, stream, PART, NB);
    hipLaunchKernelGGL(scan_add, dim3(NB), dim3(256), 0, stream, LEXCL, PART, STARTS, CURSOR, N, NB);
    hipLaunchKernelGGL(scatter_kernel, dim3(eg), dim3(256), 0, stream, src, dst, CURSOR, DSTS, E);

    // ---- fold weights (bf16 out)
    hipLaunchKernelGGL(wcomb1_kernel, dim3((HF * IN_DIM + 255) / 256), dim3(256),
                       0, stream, Wlin_h, Wseq_h, WC1);
    hipLaunchKernelGGL(wcomb2_kernel, dim3((OUT_DIM * HF + 255) / 256), dim3(256),
                       0, stream, Wlin_c, Wseq_c, WC2);

    // ---- layer 1: S1 = x @ Wc1^T  (BM=64, BN=128 column split; fused f1/f2)
    hipLaunchKernelGGL((gemm_f32a<128, IN_DIM, 4>), dim3((N + 63) / 64, 2), dim3(256),
                       0, stream, x, WC1, S1, N, HF,
                       a1_h, b1_h, a2_h, b2_h, F1, F2);

    // ---- gather layer 1 (inline coef + normalize + bias + ELU) -> HCAT bf16
    hipLaunchKernelGGL(gather1_kernel, dim3((N + 3) / 4), dim3(256), 0, stream,
                       STARTS, DSTS, F1, F2, S1, bias_h, HCAT, N);

    // ---- classifier: S2 = hcat @ Wc2^T  (BM=64; fused f1c/f2c)
    hipLaunchKernelGGL((gemm_bf16<OUT_DIM, HF, 1>), dim3((N + 63) / 64, 1), dim3(256),
                       0, stream, HCAT, WC2, S2, N, OUT_DIM,
                       a1_c, b1_c, a2_c, b2_c, F1c, F2c);

    // ---- gather classifier (inline coef + normalize + bias) -> out fp32
    hipLaunchKernelGGL(gather2_kernel, dim3((N + 3) / 4), dim3(256), 0, stream,
                       STARTS, DSTS, F1c, F2c, S2, bias_c, out, N);
}

// Round 11
// 248.130 us; speedup vs baseline: 1.0938x; 1.0560x over previous
//
#include <hip/hip_runtime.h>
#include <hip/hip_bf16.h>
#include <cstddef>
#include <cstdint>

#define IN_DIM 512
#define R_DIM 128
#define F_DIM 64
#define H_NUM 4
#define OUT_DIM 64
#define HF 256  // H_NUM * F_DIM

typedef __attribute__((ext_vector_type(4))) float f32x4;
typedef __attribute__((ext_vector_type(8))) short bf16x8;

typedef const __attribute__((address_space(1))) void gas_void;
typedef __attribute__((address_space(3))) void las_void;

__device__ __forceinline__ float bf2f(ushort u) {
    union { uint i; float f; } v; v.i = ((uint)u) << 16; return v.f;
}
__device__ __forceinline__ ushort f2bf(float f) {
    union { float f; uint i; } v; v.f = f;
    uint r = v.i + 0x7fff + ((v.i >> 16) & 1);
    return (ushort)(r >> 16);
}
__device__ __forceinline__ float u2f(uint u) {
    union { uint i; float f; } v; v.i = u; return v.f;
}

// ---------------------------------------------------------------- zero ints
__global__ __launch_bounds__(256) void zero_i32(int* __restrict__ p, int n) {
    int i = blockIdx.x * 256 + threadIdx.x;
    if (i < n) p[i] = 0;
}

// --------------------------- fold W_seq @ W_lin, both layers in one launch
__global__ __launch_bounds__(256) void wcomb_kernel(const float* __restrict__ WlinH,
                                                    const float* __restrict__ WseqH,
                                                    const float* __restrict__ WlinC,
                                                    const float* __restrict__ WseqC,
                                                    ushort* __restrict__ Wc1,
                                                    ushort* __restrict__ Wc2) {
    int idx = blockIdx.x * 256 + threadIdx.x;
    if (idx < H_NUM * F_DIM * IN_DIM) {
        int i  = idx & (IN_DIM - 1);
        int hf = idx >> 9;          // h*64 + f
        int h  = hf >> 6;
        const float* ws = WseqH + (size_t)hf * R_DIM;
        const float* wl = WlinH + (size_t)h * R_DIM * IN_DIM + i;
        float acc = 0.0f;
#pragma unroll 8
        for (int r = 0; r < R_DIM; ++r) acc += ws[r] * wl[(size_t)r * IN_DIM];
        Wc1[idx] = f2bf(acc);
    } else {
        int idx2 = idx - H_NUM * F_DIM * IN_DIM;
        if (idx2 >= OUT_DIM * HF) return;
        int j = idx2 & (HF - 1);
        int o = idx2 >> 8;
        const float* ws = WseqC + (size_t)o * R_DIM;
        const float* wl = WlinC + j;
        float acc = 0.0f;
#pragma unroll 8
        for (int r = 0; r < R_DIM; ++r) acc += ws[r] * wl[(size_t)r * HF];
        Wc2[idx2] = f2bf(acc);
    }
}

// ----------------------------- bf16 MFMA GEMM TN, fp32 A converted in-flight
// BM=64, BN=128, BK=64, 256 threads, single-buffer LDS. 1-D grid with
// XCD-paired swizzle: blocks (bx,0) and (bx,1) run 8 apart -> same XCD ->
// second A-row read hits that XCD's L2. Fused f1/f2 epilogue (2 heads/blk).
template<int BN, int K, int FS>
__global__ __launch_bounds__(256) void gemm_f32a(const float* __restrict__ A,
                                                 const ushort* __restrict__ B,
                                                 ushort* __restrict__ C,
                                                 int M, int Ntot,
                                                 const float* __restrict__ a1,
                                                 const float* __restrict__ b1,
                                                 const float* __restrict__ a2,
                                                 const float* __restrict__ b2,
                                                 float* __restrict__ f1o,
                                                 float* __restrict__ f2o) {
    constexpr int NF = BN / 16;
    constexpr int HH = BN / 64;
    __shared__ ushort As[64 * 64];
    __shared__ ushort Bs[BN * 64];
    const int tid = threadIdx.x;
    const int wave = tid >> 6;
    const int lane = tid & 63;
    const int lr = lane & 15;
    const int lg = lane >> 4;

    // XCD-paired swizzle: b -> (bx, by) with b and b+8 sharing bx, same XCD
    const int b = blockIdx.x;
    const int by = (b >> 3) & 1;
    const int bx = (b >> 4) * 8 + (b & 7);
    const int nbx = (M + 63) >> 6;
    if (bx >= nbx) return;
    const int m0 = bx * 64;
    const int n0 = by * BN;
    const int h0 = by * HH;

    int base[2];
#pragma unroll
    for (int ks = 0; ks < 2; ++ks)
        base[ks] = lr * 128 + (((ks * 4 + lg) ^ (lr & 7)) * 16);
    const int abase0 = wave * 2048 + base[0];
    const int abase1 = wave * 2048 + base[1];

    // A staging geometry (constant per thread)
    int s_grow[2], s_ldsoff[2], s_goff[2];
#pragma unroll
    for (int r = 0; r < 2; ++r) {
        int off = r * 4096 + tid * 16;
        int row = off >> 7;
        int lchunk = (off >> 4) & 7;
        int grow = m0 + row;
        if (grow >= M) grow = M - 1;
        s_grow[r] = grow;
        s_goff[r] = lchunk * 8;
        s_ldsoff[r] = row * 128 + ((lchunk ^ (row & 7)) * 16);
    }

    f32x4 acc[NF];
#pragma unroll
    for (int cb = 0; cb < NF; ++cb) acc[cb] = (f32x4)0.0f;

    for (int k0 = 0; k0 < K; k0 += 64) {
        // ---- stage B via global_load_lds (pre-swizzled source)
#pragma unroll
        for (int r = 0; r < BN / 32; ++r) {
            int off = r * 4096 + tid * 16;
            int row = off >> 7;
            int kch = ((off >> 4) & 7) ^ (row & 7);
            const ushort* g = B + (size_t)(n0 + row) * K + k0 + kch * 8;
            __builtin_amdgcn_global_load_lds((gas_void*)g,
                                             (las_void*)((char*)Bs + off), 16, 0, 0);
        }
        // ---- stage A: fp32 load -> bf16 cvt -> swizzled ds_write
#pragma unroll
        for (int r = 0; r < 2; ++r) {
            const float* g = A + (size_t)s_grow[r] * K + k0 + s_goff[r];
            float4 v0 = *(const float4*)(g);
            float4 v1 = *(const float4*)(g + 4);
            ushort us[8] = {f2bf(v0.x), f2bf(v0.y), f2bf(v0.z), f2bf(v0.w),
                            f2bf(v1.x), f2bf(v1.y), f2bf(v1.z), f2bf(v1.w)};
            *(uint4*)((char*)As + s_ldsoff[r]) = *(const uint4*)us;
        }
        __syncthreads();
        {
            bf16x8 af0 = *(const bf16x8*)((const char*)As + abase0);
            bf16x8 af1 = *(const bf16x8*)((const char*)As + abase1);
#pragma unroll
            for (int cg = 0; cg < NF / 4; ++cg) {
                bf16x8 bfr[4];
#pragma unroll
                for (int j = 0; j < 4; ++j)
                    bfr[j] = *(const bf16x8*)((const char*)Bs + (cg * 4 + j) * 2048 + base[0]);
#pragma unroll
                for (int j = 0; j < 4; ++j)
                    acc[cg * 4 + j] = __builtin_amdgcn_mfma_f32_16x16x32_bf16(
                        af0, bfr[j], acc[cg * 4 + j], 0, 0, 0);
#pragma unroll
                for (int j = 0; j < 4; ++j)
                    bfr[j] = *(const bf16x8*)((const char*)Bs + (cg * 4 + j) * 2048 + base[1]);
#pragma unroll
                for (int j = 0; j < 4; ++j)
                    acc[cg * 4 + j] = __builtin_amdgcn_mfma_f32_16x16x32_bf16(
                        af1, bfr[j], acc[cg * 4 + j], 0, 0, 0);
            }
        }
        __syncthreads();
    }

    // ---- epilogue: C store + fused f1/f2 dots for this block's heads
    float a1v[NF], a2v[NF];
#pragma unroll
    for (int cb = 0; cb < NF; ++cb) {
        int col = n0 + cb * 16 + lr;
        a1v[cb] = a1[col];
        a2v[cb] = a2[col];
    }
    const int rowb = m0 + wave * 16 + lg * 4;
#pragma unroll
    for (int r = 0; r < 4; ++r) {
        int row = rowb + r;
        bool ok = row < M;
#pragma unroll
        for (int hh = 0; hh < HH; ++hh) {
            float p1 = 0.f, p2 = 0.f;
#pragma unroll
            for (int c4 = 0; c4 < 4; ++c4) {
                int cb = hh * 4 + c4;
                float v = acc[cb][r];
                p1 += v * a1v[cb];
                p2 += v * a2v[cb];
                if (ok) C[(size_t)row * Ntot + n0 + cb * 16 + lr] = f2bf(v);
            }
#pragma unroll
            for (int m = 1; m < 16; m <<= 1) {
                p1 += __shfl_xor(p1, m, 64);
                p2 += __shfl_xor(p2, m, 64);
            }
            if (lr == 0 && ok) {
                f1o[(size_t)row * FS + h0 + hh] = p1 + b1[h0 + hh];
                f2o[(size_t)row * FS + h0 + hh] = p2 + b2[h0 + hh];
            }
        }
    }
}

// --------------------------- bf16 MFMA GEMM TN with fused f1/f2 epilogue
// BM=64, single-buffer LDS (16 KB), gload_lds both operands.
template<int BN, int K, int FS>
__global__ __launch_bounds__(256) void gemm_bf16(const ushort* __restrict__ A,
                                                 const ushort* __restrict__ B,
                                                 ushort* __restrict__ C,
                                                 int M, int Ntot,
                                                 const float* __restrict__ a1,
                                                 const float* __restrict__ b1,
                                                 const float* __restrict__ a2,
                                                 const float* __restrict__ b2,
                                                 float* __restrict__ f1o,
                                                 float* __restrict__ f2o) {
    constexpr int NF = BN / 16;
    constexpr int HH = BN / 64;
    __shared__ ushort As[64 * 64];
    __shared__ ushort Bs[BN * 64];
    const int tid = threadIdx.x;
    const int wave = tid >> 6;
    const int lane = tid & 63;
    const int lr = lane & 15;
    const int lg = lane >> 4;
    const int m0 = blockIdx.x * 64;

    int base[2];
#pragma unroll
    for (int ks = 0; ks < 2; ++ks)
        base[ks] = lr * 128 + (((ks * 4 + lg) ^ (lr & 7)) * 16);
    const int abase0 = wave * 2048 + base[0];
    const int abase1 = wave * 2048 + base[1];

    f32x4 acc[NF];
#pragma unroll
    for (int cb = 0; cb < NF; ++cb) acc[cb] = (f32x4)0.0f;

    for (int k0 = 0; k0 < K; k0 += 64) {
#pragma unroll
        for (int r = 0; r < 2; ++r) {
            int off = r * 4096 + tid * 16;
            int row = off >> 7;
            int kch = ((off >> 4) & 7) ^ (row & 7);
            const ushort* g = A + (size_t)(m0 + row) * K + k0 + kch * 8;
            __builtin_amdgcn_global_load_lds((gas_void*)g,
                                             (las_void*)((char*)As + off), 16, 0, 0);
        }
#pragma unroll
        for (int r = 0; r < BN / 32; ++r) {
            int off = r * 4096 + tid * 16;
            int row = off >> 7;
            int kch = ((off >> 4) & 7) ^ (row & 7);
            const ushort* g = B + (size_t)row * K + k0 + kch * 8;
            __builtin_amdgcn_global_load_lds((gas_void*)g,
                                             (las_void*)((char*)Bs + off), 16, 0, 0);
        }
        __syncthreads();
        {
            bf16x8 af0 = *(const bf16x8*)((const char*)As + abase0);
            bf16x8 af1 = *(const bf16x8*)((const char*)As + abase1);
#pragma unroll
            for (int cg = 0; cg < NF / 4; ++cg) {
                bf16x8 bfr[4];
#pragma unroll
                for (int j = 0; j < 4; ++j)
                    bfr[j] = *(const bf16x8*)((const char*)Bs + (cg * 4 + j) * 2048 + base[0]);
#pragma unroll
                for (int j = 0; j < 4; ++j)
                    acc[cg * 4 + j] = __builtin_amdgcn_mfma_f32_16x16x32_bf16(
                        af0, bfr[j], acc[cg * 4 + j], 0, 0, 0);
#pragma unroll
                for (int j = 0; j < 4; ++j)
                    bfr[j] = *(const bf16x8*)((const char*)Bs + (cg * 4 + j) * 2048 + base[1]);
#pragma unroll
                for (int j = 0; j < 4; ++j)
                    acc[cg * 4 + j] = __builtin_amdgcn_mfma_f32_16x16x32_bf16(
                        af1, bfr[j], acc[cg * 4 + j], 0, 0, 0);
            }
        }
        __syncthreads();
    }

    float a1v[NF], a2v[NF];
#pragma unroll
    for (int cb = 0; cb < NF; ++cb) {
        int col = cb * 16 + lr;
        a1v[cb] = a1[col];
        a2v[cb] = a2[col];
    }
    const int rowb = m0 + wave * 16 + lg * 4;
#pragma unroll
    for (int r = 0; r < 4; ++r) {
        int row = rowb + r;
        bool ok = row < M;
#pragma unroll
        for (int hh = 0; hh < HH; ++hh) {
            float p1 = 0.f, p2 = 0.f;
#pragma unroll
            for (int c4 = 0; c4 < 4; ++c4) {
                int cb = hh * 4 + c4;
                float v = acc[cb][r];
                p1 += v * a1v[cb];
                p2 += v * a2v[cb];
                if (ok) C[(size_t)row * Ntot + cb * 16 + lr] = f2bf(v);
            }
#pragma unroll
            for (int m = 1; m < 16; m <<= 1) {
                p1 += __shfl_xor(p1, m, 64);
                p2 += __shfl_xor(p2, m, 64);
            }
            if (lr == 0 && ok) {
                f1o[(size_t)row * FS + hh] = p1 + b1[hh];
                f2o[(size_t)row * FS + hh] = p2 + b2[hh];
            }
        }
    }
}

// ------------------------------------------------------------ CSR: histogram
__global__ __launch_bounds__(256) void hist_kernel(const int* __restrict__ src,
                                                   int* __restrict__ counts, int E) {
    int e = blockIdx.x * 256 + threadIdx.x;
    if (e < E) atomicAdd(&counts[src[e]], 1);
}

// ----------------------------------------- scan stage 1: per-block excl scan
__global__ __launch_bounds__(256) void scan_blk(const int* __restrict__ counts,
                                                int* __restrict__ lexcl,
                                                int* __restrict__ part, int N) {
    __shared__ int wsum[4];
    int t = threadIdx.x;
    int g = blockIdx.x * 256 + t;
    int lane = t & 63, wid = t >> 6;
    int v = (g < N) ? counts[g] : 0;
    int x = v;
#pragma unroll
    for (int off = 1; off < 64; off <<= 1) {
        int u = __shfl_up(x, off, 64);
        if (lane >= off) x += u;
    }
    if (lane == 63) wsum[wid] = x;
    __syncthreads();
    int woff = 0;
#pragma unroll
    for (int w = 0; w < 3; ++w) if (w < wid) woff += wsum[w];
    int incl = x + woff;
    if (g < N) lexcl[g] = incl - v;
    if (t == 255) part[blockIdx.x] = incl;
}

// --------------------------------- scan stage 2: excl scan of block partials
__global__ __launch_bounds__(256) void scan_part(int* __restrict__ part, int nb) {
    __shared__ int wsum[4];
    int t = threadIdx.x;
    int lane = t & 63, wid = t >> 6;
    int v = (t < nb) ? part[t] : 0;
    int x = v;
#pragma unroll
    for (int off = 1; off < 64; off <<= 1) {
        int u = __shfl_up(x, off, 64);
        if (lane >= off) x += u;
    }
    if (lane == 63) wsum[wid] = x;
    __syncthreads();
    int woff = 0;
#pragma unroll
    for (int w = 0; w < 3; ++w) if (w < wid) woff += wsum[w];
    int incl = x + woff;
    __syncthreads();
    if (t < nb) part[t] = incl - v;
    if (t == 255) part[nb] = incl;   // grand total
}

// ------------------------------------- scan stage 3: add offsets, emit CSR ptrs
__global__ __launch_bounds__(256) void scan_add(const int* __restrict__ lexcl,
                                                const int* __restrict__ part,
                                                int* __restrict__ starts,
                                                int* __restrict__ cursor, int N, int nb) {
    int g = blockIdx.x * 256 + threadIdx.x;
    if (g < N) {
        int s = lexcl[g] + part[blockIdx.x];
        starts[g] = s;
        cursor[g] = s;
    }
    if (g == 0) starts[N] = part[nb];
}

// ------------------------- CSR: position scatter (writes sorted dst directly)
__global__ __launch_bounds__(256) void scatter_kernel(const int* __restrict__ src,
                                                      const int* __restrict__ dst,
                                                      int* __restrict__ cursor,
                                                      int* __restrict__ dsts, int E) {
    int e = blockIdx.x * 256 + threadIdx.x;
    if (e >= E) return;
    int p = atomicAdd(&cursor[src[e]], 1);
    dsts[p] = dst[e];
}

// ----------------------- gather + normalize + bias + ELU, heads (wave/node)
// 2 edges per pass: half-wave es handles edge i+es; lane owns 8 features
// (fl*8..+7, head = fl>>3) -> one uint4 (16B) row load per edge -> 1KB/instr.
__global__ __launch_bounds__(256) void gather1_kernel(const int* __restrict__ starts,
                                                      const int* __restrict__ dsts,
                                                      const float* __restrict__ f1,
                                                      const float* __restrict__ f2,
                                                      const ushort* __restrict__ S1,
                                                      const float* __restrict__ bias,
                                                      ushort* __restrict__ hcat, int N) {
    int n = (int)((blockIdx.x * blockDim.x + threadIdx.x) >> 6);
    int lane = threadIdx.x & 63;
    if (n >= N) return;
    const int es = lane >> 5;      // edge slot 0/1
    const int fl = lane & 31;      // feature lane: feats fl*8..fl*8+7
    const int head = fl >> 3;
    const float f1h = f1[(size_t)n * 4 + head];
    int beg = starts[n], end = starts[n + 1];
    float a[8] = {};
    float den = 0.f;
    int i = beg;

#define G1_EDGE(D)                                                            \
    {                                                                         \
        float g_ = f2[(size_t)(D) * 4 + head];                                \
        uint4 r_ = *(const uint4*)(S1 + (size_t)(D) * HF + fl * 8);           \
        float l_ = f1h + g_; l_ = l_ > 0.f ? l_ : 0.2f * l_;                  \
        float c_ = __expf(l_);                                                \
        a[0] += c_ * u2f(r_.x << 16);  a[1] += c_ * u2f(r_.x & 0xffff0000u);  \
        a[2] += c_ * u2f(r_.y << 16);  a[3] += c_ * u2f(r_.y & 0xffff0000u);  \
        a[4] += c_ * u2f(r_.z << 16);  a[5] += c_ * u2f(r_.z & 0xffff0000u);  \
        a[6] += c_ * u2f(r_.w << 16);  a[7] += c_ * u2f(r_.w & 0xffff0000u);  \
        den += c_;                                                            \
    }

    for (; i + 4 <= end; i += 4) {       // 4 edges: 2 passes in flight
        int dA = dsts[i + es];
        int dB = dsts[i + 2 + es];
        G1_EDGE(dA);
        G1_EDGE(dB);
    }
    if (i + 2 <= end) {                  // one 2-edge pass
        int d = dsts[i + es];
        G1_EDGE(d);
        i += 2;
    }
    if (i < end && es == 0) {            // final single edge, half-wave
        int d = dsts[i];
        G1_EDGE(d);
    }
#undef G1_EDGE

    // combine the two edge-slots
#pragma unroll
    for (int k = 0; k < 8; ++k) a[k] += __shfl_xor(a[k], 32, 64);
    den += __shfl_xor(den, 32, 64);

    if (es == 0) {
        float rd = __builtin_amdgcn_rcpf(den);
        float4 b0 = *(const float4*)(bias + fl * 8);
        float4 b1 = *(const float4*)(bias + fl * 8 + 4);
        float v[8];
        v[0] = a[0] * rd + b0.x; v[1] = a[1] * rd + b0.y;
        v[2] = a[2] * rd + b0.z; v[3] = a[3] * rd + b0.w;
        v[4] = a[4] * rd + b1.x; v[5] = a[5] * rd + b1.y;
        v[6] = a[6] * rd + b1.z; v[7] = a[7] * rd + b1.w;
        ushort us[8];
#pragma unroll
        for (int k = 0; k < 8; ++k) {
            float vv = v[k] > 0.f ? v[k] : __expf(v[k]) - 1.f;
            us[k] = f2bf(vv);
        }
        *(uint4*)(hcat + (size_t)n * HF + fl * 8) = *(const uint4*)us;
    }
}

// --------------------------- gather + normalize + bias, classifier (wave/node)
// 2 edges per pass: half-wave per edge; lane owns 2 features (fl*2, fl*2+1).
__global__ __launch_bounds__(256) void gather2_kernel(const int* __restrict__ starts,
                                                      const int* __restrict__ dsts,
                                                      const float* __restrict__ f1,
                                                      const float* __restrict__ f2,
                                                      const ushort* __restrict__ S2,
                                                      const float* __restrict__ bias,
                                                      float* __restrict__ out, int N) {
    int n = (int)((blockIdx.x * blockDim.x + threadIdx.x) >> 6);
    int lane = threadIdx.x & 63;
    if (n >= N) return;
    const int es = lane >> 5;
    const int fl = lane & 31;
    const float f1u = f1[n];
    int beg = starts[n], end = starts[n + 1];
    float a0 = 0.f, a1 = 0.f, den = 0.f;
    int i = beg;

#define G2_EDGE(D)                                                            \
    {                                                                         \
        float g_ = f2[(D)];                                                   \
        uint r_ = *(const uint*)(S2 + (size_t)(D) * OUT_DIM + fl * 2);        \
        float l_ = f1u + g_; l_ = l_ > 0.f ? l_ : 0.2f * l_;                  \
        float c_ = __expf(l_);                                                \
        a0 += c_ * u2f(r_ << 16);                                             \
        a1 += c_ * u2f(r_ & 0xffff0000u);                                     \
        den += c_;                                                            \
    }

    for (; i + 4 <= end; i += 4) {
        int dA = dsts[i + es];
        int dB = dsts[i + 2 + es];
        G2_EDGE(dA);
        G2_EDGE(dB);
    }
    if (i + 2 <= end) {
        int d = dsts[i + es];
        G2_EDGE(d);
        i += 2;
    }
    if (i < end && es == 0) {
        int d = dsts[i];
        G2_EDGE(d);
    }
#undef G2_EDGE

    a0 += __shfl_xor(a0, 32, 64);
    a1 += __shfl_xor(a1, 32, 64);
    den += __shfl_xor(den, 32, 64);

    if (es == 0) {
        float rd = __builtin_amdgcn_rcpf(den);
        float2 b = *(const float2*)(bias + fl * 2);
        float2 o;
        o.x = a0 * rd + b.x;
        o.y = a1 * rd + b.y;
        *(float2*)(out + (size_t)n * OUT_DIM + fl * 2) = o;
    }
}

// ===========================================================================
extern "C" void kernel_launch(void* const* d_in, const int* in_sizes, int n_in,
                              void* d_out, int out_size, void* d_ws, size_t ws_size,
                              hipStream_t stream) {
    const float* x      = (const float*)d_in[0];
    const int*   edges  = (const int*)d_in[1];
    const float* Wlin_h = (const float*)d_in[2];
    const float* Wseq_h = (const float*)d_in[3];
    const float* a1_h   = (const float*)d_in[4];
    const float* b1_h   = (const float*)d_in[5];
    const float* a2_h   = (const float*)d_in[6];
    const float* b2_h   = (const float*)d_in[7];
    const float* bias_h = (const float*)d_in[8];
    const float* Wlin_c = (const float*)d_in[9];
    const float* Wseq_c = (const float*)d_in[10];
    const float* a1_c   = (const float*)d_in[11];
    const float* b1_c   = (const float*)d_in[12];
    const float* a2_c   = (const float*)d_in[13];
    const float* b2_c   = (const float*)d_in[14];
    const float* bias_c = (const float*)d_in[15];

    const int N = in_sizes[0] / IN_DIM;
    const int E = in_sizes[1] / 2;
    const int* src = edges;
    const int* dst = edges + E;

    char* ws = (char*)d_ws;
    size_t off = 0;
    ushort* WC1   = (ushort*)(ws + off); off += (size_t)HF * IN_DIM * 2;
    ushort* WC2   = (ushort*)(ws + off); off += (size_t)OUT_DIM * HF * 2;
    ushort* S1    = (ushort*)(ws + off); off += (size_t)N * HF * 2;
    ushort* S2    = S1;  // S1 dead after gather1; reuse for S2 [N][64]
    ushort* HCAT  = (ushort*)(ws + off); off += (size_t)N * HF * 2;
    float*  F1    = (float*)(ws + off);  off += (size_t)N * H_NUM * 4;
    float*  F2    = (float*)(ws + off);  off += (size_t)N * H_NUM * 4;
    float*  F1c   = (float*)(ws + off);  off += (size_t)N * 4;
    float*  F2c   = (float*)(ws + off);  off += (size_t)N * 4;
    int* COUNTS   = (int*)(ws + off);    off += (size_t)N * 4;
    int* STARTS   = (int*)(ws + off);    off += ((size_t)N + 1) * 4;
    int* CURSOR   = (int*)(ws + off);    off += (size_t)N * 4;
    int* DSTS     = (int*)(ws + off);    off += (size_t)E * 4;
    int* LEXCL    = (int*)(ws + off);    off += (size_t)N * 4;
    int* PART     = (int*)(ws + off);    off += 512 * 4;

    float* out = (float*)d_out;

    const int eg = (E + 255) / 256;
    const int NB = (N + 255) / 256;

    // ---- CSR build (shared by both layers); DSTS = dst sorted by src
    hipLaunchKernelGGL(zero_i32, dim3(NB), dim3(256), 0, stream, COUNTS, N);
    hipLaunchKernelGGL(hist_kernel, dim3(eg), dim3(256), 0, stream, src, COUNTS, E);
    hipLaunchKernelGGL(scan_blk, dim3(NB), dim3(256), 0, stream, COUNTS, LEXCL, PART, N);
    hipLaunchKernelGGL(scan_part, dim3(1), dim3(256), 0, stream, PART, NB);
    hipLaunchKernelGGL(scan_add, dim3(NB), dim3(256), 0, stream, LEXCL, PART, STARTS, CURSOR, N, NB);
    hipLaunchKernelGGL(scatter_kernel, dim3(eg), dim3(256), 0, stream, src, dst, CURSOR, DSTS, E);

    // ---- fold weights, both layers (bf16 out)
    hipLaunchKernelGGL(wcomb_kernel,
                       dim3((H_NUM * F_DIM * IN_DIM + OUT_DIM * HF + 255) / 256), dim3(256),
                       0, stream, Wlin_h, Wseq_h, Wlin_c, Wseq_c, WC1, WC2);

    // ---- layer 1: S1 = x @ Wc1^T  (XCD-paired swizzled 1-D grid; fused f1/f2)
    {
        int nbx = (N + 63) / 64;
        int gx = 16 * ((nbx + 7) / 8);
        hipLaunchKernelGGL((gemm_f32a<128, IN_DIM, 4>), dim3(gx), dim3(256),
                           0, stream, x, WC1, S1, N, HF,
                           a1_h, b1_h, a2_h, b2_h, F1, F2);
    }

    // ---- gather layer 1 (inline coef + normalize + bias + ELU) -> HCAT bf16
    hipLaunchKernelGGL(gather1_kernel, dim3((N + 3) / 4), dim3(256), 0, stream,
                       STARTS, DSTS, F1, F2, S1, bias_h, HCAT, N);

    // ---- classifier: S2 = hcat @ Wc2^T  (BM=64; fused f1c/f2c)
    hipLaunchKernelGGL((gemm_bf16<OUT_DIM, HF, 1>), dim3((N + 63) / 64, 1), dim3(256),
                       0, stream, HCAT, WC2, S2, N, OUT_DIM,
                       a1_c, b1_c, a2_c, b2_c, F1c, F2c);

    // ---- gather classifier (inline coef + normalize + bias) -> out fp32
    hipLaunchKernelGGL(gather2_kernel, dim3((N + 3) / 4), dim3(256), 0, stream,
                       STARTS, DSTS, F1c, F2c, S2, bias_c, out, N);
}

// Round 12
// 243.698 us; speedup vs baseline: 1.1137x; 1.0182x over previous
//
#include <hip/hip_runtime.h>
#include <hip/hip_bf16.h>
#include <cstddef>
#include <cstdint>

#define IN_DIM 512
#define R_DIM 128
#define F_DIM 64
#define H_NUM 4
#define OUT_DIM 64
#define HF 256  // H_NUM * F_DIM

typedef __attribute__((ext_vector_type(4))) float f32x4;
typedef __attribute__((ext_vector_type(8))) short bf16x8;

typedef const __attribute__((address_space(1))) void gas_void;
typedef __attribute__((address_space(3))) void las_void;

__device__ __forceinline__ float bf2f(ushort u) {
    union { uint i; float f; } v; v.i = ((uint)u) << 16; return v.f;
}
__device__ __forceinline__ ushort f2bf(float f) {
    union { float f; uint i; } v; v.f = f;
    uint r = v.i + 0x7fff + ((v.i >> 16) & 1);
    return (ushort)(r >> 16);
}
__device__ __forceinline__ float u2f(uint u) {
    union { uint i; float f; } v; v.i = u; return v.f;
}

// ---------------------------------------------------------------- zero ints
__global__ __launch_bounds__(256) void zero_i32(int* __restrict__ p, int n) {
    int i = blockIdx.x * 256 + threadIdx.x;
    if (i < n) p[i] = 0;
}

// --------------------------- fold W_seq @ W_lin, both layers in one launch
__global__ __launch_bounds__(256) void wcomb_kernel(const float* __restrict__ WlinH,
                                                    const float* __restrict__ WseqH,
                                                    const float* __restrict__ WlinC,
                                                    const float* __restrict__ WseqC,
                                                    ushort* __restrict__ Wc1,
                                                    ushort* __restrict__ Wc2) {
    int idx = blockIdx.x * 256 + threadIdx.x;
    if (idx < H_NUM * F_DIM * IN_DIM) {
        int i  = idx & (IN_DIM - 1);
        int hf = idx >> 9;          // h*64 + f
        int h  = hf >> 6;
        const float* ws = WseqH + (size_t)hf * R_DIM;
        const float* wl = WlinH + (size_t)h * R_DIM * IN_DIM + i;
        float acc = 0.0f;
#pragma unroll 8
        for (int r = 0; r < R_DIM; ++r) acc += ws[r] * wl[(size_t)r * IN_DIM];
        Wc1[idx] = f2bf(acc);
    } else {
        int idx2 = idx - H_NUM * F_DIM * IN_DIM;
        if (idx2 >= OUT_DIM * HF) return;
        int j = idx2 & (HF - 1);
        int o = idx2 >> 8;
        const float* ws = WseqC + (size_t)o * R_DIM;
        const float* wl = WlinC + j;
        float acc = 0.0f;
#pragma unroll 8
        for (int r = 0; r < R_DIM; ++r) acc += ws[r] * wl[(size_t)r * HF];
        Wc2[idx2] = f2bf(acc);
    }
}

// ----------------------------- bf16 MFMA GEMM TN, fp32 A converted in-flight
// BM=32, BN=128, BK=64, 256 threads. LDS = 4KB A + 16KB B = 20KB ->
// 8 blocks/CU (32 waves, full occupancy). Wave layout: (wave&1) = 16-row
// half, (wave>>1) = 64-col head. Fused f1/f2 epilogue, one head per wave.
// 1-D grid, XCD-paired swizzle (b and b+8 share A rows on one XCD).
template<int BN, int K, int FS>
__global__ __launch_bounds__(256) void gemm_f32a(const float* __restrict__ A,
                                                 const ushort* __restrict__ B,
                                                 ushort* __restrict__ C,
                                                 int M, int Ntot,
                                                 const float* __restrict__ a1,
                                                 const float* __restrict__ b1,
                                                 const float* __restrict__ a2,
                                                 const float* __restrict__ b2,
                                                 float* __restrict__ f1o,
                                                 float* __restrict__ f2o) {
    constexpr int NF = 4;            // 4 col-blocks (one head) per wave
    __shared__ ushort As[32 * 64];
    __shared__ ushort Bs[BN * 64];
    const int tid = threadIdx.x;
    const int wave = tid >> 6;
    const int lane = tid & 63;
    const int lr = lane & 15;
    const int lg = lane >> 4;
    const int wr = wave & 1;         // row half
    const int wc = wave >> 1;        // col half (= head within block)

    // XCD-paired swizzle: b -> (bx, by); b and b+8 share bx -> same XCD
    const int b = blockIdx.x;
    const int by = (b >> 3) & 1;
    const int bx = (b >> 4) * 8 + (b & 7);
    const int nbx = (M + 31) >> 5;
    if (bx >= nbx) return;
    const int m0 = bx * 32;
    const int n0 = by * BN;
    const int h0 = by * 2;           // 2 heads per 128-col block

    int base[2];
#pragma unroll
    for (int ks = 0; ks < 2; ++ks)
        base[ks] = lr * 128 + (((ks * 4 + lg) ^ (lr & 7)) * 16);
    const int abase0 = wr * 2048 + base[0];
    const int abase1 = wr * 2048 + base[1];

    // A staging geometry: 1 round, 256 threads x 16B = 4KB
    const int s_row = tid >> 3;              // 0..31
    const int s_lchunk = tid & 7;
    int s_grow = m0 + s_row;
    if (s_grow >= M) s_grow = M - 1;         // clamp (never stored)
    const int s_ldsoff = s_row * 128 + ((s_lchunk ^ (s_row & 7)) * 16);
    const int s_goff = s_lchunk * 8;

    f32x4 acc[NF];
#pragma unroll
    for (int cb = 0; cb < NF; ++cb) acc[cb] = (f32x4)0.0f;

    for (int k0 = 0; k0 < K; k0 += 64) {
        // ---- stage B via global_load_lds (pre-swizzled source), 4 rounds
#pragma unroll
        for (int r = 0; r < BN / 32; ++r) {
            int off = r * 4096 + tid * 16;
            int row = off >> 7;
            int kch = ((off >> 4) & 7) ^ (row & 7);
            const ushort* g = B + (size_t)(n0 + row) * K + k0 + kch * 8;
            __builtin_amdgcn_global_load_lds((gas_void*)g,
                                             (las_void*)((char*)Bs + off), 16, 0, 0);
        }
        // ---- stage A: fp32 load -> bf16 cvt -> swizzled ds_write, 1 round
        {
            const float* g = A + (size_t)s_grow * K + k0 + s_goff;
            float4 v0 = *(const float4*)(g);
            float4 v1 = *(const float4*)(g + 4);
            ushort us[8] = {f2bf(v0.x), f2bf(v0.y), f2bf(v0.z), f2bf(v0.w),
                            f2bf(v1.x), f2bf(v1.y), f2bf(v1.z), f2bf(v1.w)};
            *(uint4*)((char*)As + s_ldsoff) = *(const uint4*)us;
        }
        __syncthreads();
        {
            bf16x8 af0 = *(const bf16x8*)((const char*)As + abase0);
            bf16x8 af1 = *(const bf16x8*)((const char*)As + abase1);
            bf16x8 bfr[NF];
#pragma unroll
            for (int j = 0; j < NF; ++j)
                bfr[j] = *(const bf16x8*)((const char*)Bs + (wc * 4 + j) * 2048 + base[0]);
#pragma unroll
            for (int j = 0; j < NF; ++j)
                acc[j] = __builtin_amdgcn_mfma_f32_16x16x32_bf16(
                    af0, bfr[j], acc[j], 0, 0, 0);
#pragma unroll
            for (int j = 0; j < NF; ++j)
                bfr[j] = *(const bf16x8*)((const char*)Bs + (wc * 4 + j) * 2048 + base[1]);
#pragma unroll
            for (int j = 0; j < NF; ++j)
                acc[j] = __builtin_amdgcn_mfma_f32_16x16x32_bf16(
                    af1, bfr[j], acc[j], 0, 0, 0);
        }
        __syncthreads();
    }

    // ---- epilogue: C store + fused f1/f2 dot for this wave's head
    const int head = h0 + wc;
    float a1v[NF], a2v[NF];
#pragma unroll
    for (int cb = 0; cb < NF; ++cb) {
        int col = n0 + wc * 64 + cb * 16 + lr;
        a1v[cb] = a1[col];
        a2v[cb] = a2[col];
    }
    const int rowb = m0 + wr * 16 + lg * 4;
#pragma unroll
    for (int r = 0; r < 4; ++r) {
        int row = rowb + r;
        bool ok = row < M;
        float p1 = 0.f, p2 = 0.f;
#pragma unroll
        for (int cb = 0; cb < NF; ++cb) {
            float v = acc[cb][r];
            p1 += v * a1v[cb];
            p2 += v * a2v[cb];
            if (ok) C[(size_t)row * Ntot + n0 + wc * 64 + cb * 16 + lr] = f2bf(v);
        }
#pragma unroll
        for (int m = 1; m < 16; m <<= 1) {
            p1 += __shfl_xor(p1, m, 64);
            p2 += __shfl_xor(p2, m, 64);
        }
        if (lr == 0 && ok) {
            f1o[(size_t)row * FS + head] = p1 + b1[head];
            f2o[(size_t)row * FS + head] = p2 + b2[head];
        }
    }
}

// --------------------------- bf16 MFMA GEMM TN with fused f1/f2 epilogue
// BM=64, single-buffer LDS (16 KB), gload_lds both operands.
template<int BN, int K, int FS>
__global__ __launch_bounds__(256) void gemm_bf16(const ushort* __restrict__ A,
                                                 const ushort* __restrict__ B,
                                                 ushort* __restrict__ C,
                                                 int M, int Ntot,
                                                 const float* __restrict__ a1,
                                                 const float* __restrict__ b1,
                                                 const float* __restrict__ a2,
                                                 const float* __restrict__ b2,
                                                 float* __restrict__ f1o,
                                                 float* __restrict__ f2o) {
    constexpr int NF = BN / 16;
    constexpr int HH = BN / 64;
    __shared__ ushort As[64 * 64];
    __shared__ ushort Bs[BN * 64];
    const int tid = threadIdx.x;
    const int wave = tid >> 6;
    const int lane = tid & 63;
    const int lr = lane & 15;
    const int lg = lane >> 4;
    const int m0 = blockIdx.x * 64;

    int base[2];
#pragma unroll
    for (int ks = 0; ks < 2; ++ks)
        base[ks] = lr * 128 + (((ks * 4 + lg) ^ (lr & 7)) * 16);
    const int abase0 = wave * 2048 + base[0];
    const int abase1 = wave * 2048 + base[1];

    f32x4 acc[NF];
#pragma unroll
    for (int cb = 0; cb < NF; ++cb) acc[cb] = (f32x4)0.0f;

    for (int k0 = 0; k0 < K; k0 += 64) {
#pragma unroll
        for (int r = 0; r < 2; ++r) {
            int off = r * 4096 + tid * 16;
            int row = off >> 7;
            int kch = ((off >> 4) & 7) ^ (row & 7);
            const ushort* g = A + (size_t)(m0 + row) * K + k0 + kch * 8;
            __builtin_amdgcn_global_load_lds((gas_void*)g,
                                             (las_void*)((char*)As + off), 16, 0, 0);
        }
#pragma unroll
        for (int r = 0; r < BN / 32; ++r) {
            int off = r * 4096 + tid * 16;
            int row = off >> 7;
            int kch = ((off >> 4) & 7) ^ (row & 7);
            const ushort* g = B + (size_t)row * K + k0 + kch * 8;
            __builtin_amdgcn_global_load_lds((gas_void*)g,
                                             (las_void*)((char*)Bs + off), 16, 0, 0);
        }
        __syncthreads();
        {
            bf16x8 af0 = *(const bf16x8*)((const char*)As + abase0);
            bf16x8 af1 = *(const bf16x8*)((const char*)As + abase1);
#pragma unroll
            for (int cg = 0; cg < NF / 4; ++cg) {
                bf16x8 bfr[4];
#pragma unroll
                for (int j = 0; j < 4; ++j)
                    bfr[j] = *(const bf16x8*)((const char*)Bs + (cg * 4 + j) * 2048 + base[0]);
#pragma unroll
                for (int j = 0; j < 4; ++j)
                    acc[cg * 4 + j] = __builtin_amdgcn_mfma_f32_16x16x32_bf16(
                        af0, bfr[j], acc[cg * 4 + j], 0, 0, 0);
#pragma unroll
                for (int j = 0; j < 4; ++j)
                    bfr[j] = *(const bf16x8*)((const char*)Bs + (cg * 4 + j) * 2048 + base[1]);
#pragma unroll
                for (int j = 0; j < 4; ++j)
                    acc[cg * 4 + j] = __builtin_amdgcn_mfma_f32_16x16x32_bf16(
                        af1, bfr[j], acc[cg * 4 + j], 0, 0, 0);
            }
        }
        __syncthreads();
    }

    float a1v[NF], a2v[NF];
#pragma unroll
    for (int cb = 0; cb < NF; ++cb) {
        int col = cb * 16 + lr;
        a1v[cb] = a1[col];
        a2v[cb] = a2[col];
    }
    const int rowb = m0 + wave * 16 + lg * 4;
#pragma unroll
    for (int r = 0; r < 4; ++r) {
        int row = rowb + r;
        bool ok = row < M;
#pragma unroll
        for (int hh = 0; hh < HH; ++hh) {
            float p1 = 0.f, p2 = 0.f;
#pragma unroll
            for (int c4 = 0; c4 < 4; ++c4) {
                int cb = hh * 4 + c4;
                float v = acc[cb][r];
                p1 += v * a1v[cb];
                p2 += v * a2v[cb];
                if (ok) C[(size_t)row * Ntot + cb * 16 + lr] = f2bf(v);
            }
#pragma unroll
            for (int m = 1; m < 16; m <<= 1) {
                p1 += __shfl_xor(p1, m, 64);
                p2 += __shfl_xor(p2, m, 64);
            }
            if (lr == 0 && ok) {
                f1o[(size_t)row * FS + hh] = p1 + b1[hh];
                f2o[(size_t)row * FS + hh] = p2 + b2[hh];
            }
        }
    }
}

// ------------------------------------------------------------ CSR: histogram
__global__ __launch_bounds__(256) void hist_kernel(const int* __restrict__ src,
                                                   int* __restrict__ counts, int E) {
    int e = blockIdx.x * 256 + threadIdx.x;
    if (e < E) atomicAdd(&counts[src[e]], 1);
}

// ----------------------------------------- scan stage 1: per-block excl scan
__global__ __launch_bounds__(256) void scan_blk(const int* __restrict__ counts,
                                                int* __restrict__ lexcl,
                                                int* __restrict__ part, int N) {
    __shared__ int wsum[4];
    int t = threadIdx.x;
    int g = blockIdx.x * 256 + t;
    int lane = t & 63, wid = t >> 6;
    int v = (g < N) ? counts[g] : 0;
    int x = v;
#pragma unroll
    for (int off = 1; off < 64; off <<= 1) {
        int u = __shfl_up(x, off, 64);
        if (lane >= off) x += u;
    }
    if (lane == 63) wsum[wid] = x;
    __syncthreads();
    int woff = 0;
#pragma unroll
    for (int w = 0; w < 3; ++w) if (w < wid) woff += wsum[w];
    int incl = x + woff;
    if (g < N) lexcl[g] = incl - v;
    if (t == 255) part[blockIdx.x] = incl;
}

// --------------------------------- scan stage 2: excl scan of block partials
__global__ __launch_bounds__(256) void scan_part(int* __restrict__ part, int nb) {
    __shared__ int wsum[4];
    int t = threadIdx.x;
    int lane = t & 63, wid = t >> 6;
    int v = (t < nb) ? part[t] : 0;
    int x = v;
#pragma unroll
    for (int off = 1; off < 64; off <<= 1) {
        int u = __shfl_up(x, off, 64);
        if (lane >= off) x += u;
    }
    if (lane == 63) wsum[wid] = x;
    __syncthreads();
    int woff = 0;
#pragma unroll
    for (int w = 0; w < 3; ++w) if (w < wid) woff += wsum[w];
    int incl = x + woff;
    __syncthreads();
    if (t < nb) part[t] = incl - v;
    if (t == 255) part[nb] = incl;   // grand total
}

// ------------------------------------- scan stage 3: add offsets, emit CSR ptrs
__global__ __launch_bounds__(256) void scan_add(const int* __restrict__ lexcl,
                                                const int* __restrict__ part,
                                                int* __restrict__ starts,
                                                int* __restrict__ cursor, int N, int nb) {
    int g = blockIdx.x * 256 + threadIdx.x;
    if (g < N) {
        int s = lexcl[g] + part[blockIdx.x];
        starts[g] = s;
        cursor[g] = s;
    }
    if (g == 0) starts[N] = part[nb];
}

// ------------------------- CSR: position scatter (writes sorted dst directly)
__global__ __launch_bounds__(256) void scatter_kernel(const int* __restrict__ src,
                                                      const int* __restrict__ dst,
                                                      int* __restrict__ cursor,
                                                      int* __restrict__ dsts, int E) {
    int e = blockIdx.x * 256 + threadIdx.x;
    if (e >= E) return;
    int p = atomicAdd(&cursor[src[e]], 1);
    dsts[p] = dst[e];
}

// ----------------------- gather + normalize + bias + ELU, heads (wave/node)
// 2 edges per pass: half-wave es handles edge i+es; lane owns 8 features
// (fl*8..+7, head = fl>>3) -> one uint4 (16B) row load per edge -> 1KB/instr.
__global__ __launch_bounds__(256) void gather1_kernel(const int* __restrict__ starts,
                                                      const int* __restrict__ dsts,
                                                      const float* __restrict__ f1,
                                                      const float* __restrict__ f2,
                                                      const ushort* __restrict__ S1,
                                                      const float* __restrict__ bias,
                                                      ushort* __restrict__ hcat, int N) {
    int n = (int)((blockIdx.x * blockDim.x + threadIdx.x) >> 6);
    int lane = threadIdx.x & 63;
    if (n >= N) return;
    const int es = lane >> 5;      // edge slot 0/1
    const int fl = lane & 31;      // feature lane: feats fl*8..fl*8+7
    const int head = fl >> 3;
    const float f1h = f1[(size_t)n * 4 + head];
    int beg = starts[n], end = starts[n + 1];
    float a[8] = {};
    float den = 0.f;
    int i = beg;

#define G1_EDGE(D)                                                            \
    {                                                                         \
        float g_ = f2[(size_t)(D) * 4 + head];                                \
        uint4 r_ = *(const uint4*)(S1 + (size_t)(D) * HF + fl * 8);           \
        float l_ = f1h + g_; l_ = l_ > 0.f ? l_ : 0.2f * l_;                  \
        float c_ = __expf(l_);                                                \
        a[0] += c_ * u2f(r_.x << 16);  a[1] += c_ * u2f(r_.x & 0xffff0000u);  \
        a[2] += c_ * u2f(r_.y << 16);  a[3] += c_ * u2f(r_.y & 0xffff0000u);  \
        a[4] += c_ * u2f(r_.z << 16);  a[5] += c_ * u2f(r_.z & 0xffff0000u);  \
        a[6] += c_ * u2f(r_.w << 16);  a[7] += c_ * u2f(r_.w & 0xffff0000u);  \
        den += c_;                                                            \
    }

    for (; i + 4 <= end; i += 4) {       // 4 edges: 2 passes in flight
        int dA = dsts[i + es];
        int dB = dsts[i + 2 + es];
        G1_EDGE(dA);
        G1_EDGE(dB);
    }
    if (i + 2 <= end) {                  // one 2-edge pass
        int d = dsts[i + es];
        G1_EDGE(d);
        i += 2;
    }
    if (i < end && es == 0) {            // final single edge, half-wave
        int d = dsts[i];
        G1_EDGE(d);
    }
#undef G1_EDGE

    // combine the two edge-slots
#pragma unroll
    for (int k = 0; k < 8; ++k) a[k] += __shfl_xor(a[k], 32, 64);
    den += __shfl_xor(den, 32, 64);

    if (es == 0) {
        float rd = __builtin_amdgcn_rcpf(den);
        float4 b0 = *(const float4*)(bias + fl * 8);
        float4 b1 = *(const float4*)(bias + fl * 8 + 4);
        float v[8];
        v[0] = a[0] * rd + b0.x; v[1] = a[1] * rd + b0.y;
        v[2] = a[2] * rd + b0.z; v[3] = a[3] * rd + b0.w;
        v[4] = a[4] * rd + b1.x; v[5] = a[5] * rd + b1.y;
        v[6] = a[6] * rd + b1.z; v[7] = a[7] * rd + b1.w;
        ushort us[8];
#pragma unroll
        for (int k = 0; k < 8; ++k) {
            float vv = v[k] > 0.f ? v[k] : __expf(v[k]) - 1.f;
            us[k] = f2bf(vv);
        }
        *(uint4*)(hcat + (size_t)n * HF + fl * 8) = *(const uint4*)us;
    }
}

// --------------------------- gather + normalize + bias, classifier (wave/node)
// 2 edges per pass: half-wave per edge; lane owns 2 features (fl*2, fl*2+1).
__global__ __launch_bounds__(256) void gather2_kernel(const int* __restrict__ starts,
                                                      const int* __restrict__ dsts,
                                                      const float* __restrict__ f1,
                                                      const float* __restrict__ f2,
                                                      const ushort* __restrict__ S2,
                                                      const float* __restrict__ bias,
                                                      float* __restrict__ out, int N) {
    int n = (int)((blockIdx.x * blockDim.x + threadIdx.x) >> 6);
    int lane = threadIdx.x & 63;
    if (n >= N) return;
    const int es = lane >> 5;
    const int fl = lane & 31;
    const float f1u = f1[n];
    int beg = starts[n], end = starts[n + 1];
    float a0 = 0.f, a1 = 0.f, den = 0.f;
    int i = beg;

#define G2_EDGE(D)                                                            \
    {                                                                         \
        float g_ = f2[(D)];                                                   \
        uint r_ = *(const uint*)(S2 + (size_t)(D) * OUT_DIM + fl * 2);        \
        float l_ = f1u + g_; l_ = l_ > 0.f ? l_ : 0.2f * l_;                  \
        float c_ = __expf(l_);                                                \
        a0 += c_ * u2f(r_ << 16);                                             \
        a1 += c_ * u2f(r_ & 0xffff0000u);                                     \
        den += c_;                                                            \
    }

    for (; i + 4 <= end; i += 4) {
        int dA = dsts[i + es];
        int dB = dsts[i + 2 + es];
        G2_EDGE(dA);
        G2_EDGE(dB);
    }
    if (i + 2 <= end) {
        int d = dsts[i + es];
        G2_EDGE(d);
        i += 2;
    }
    if (i < end && es == 0) {
        int d = dsts[i];
        G2_EDGE(d);
    }
#undef G2_EDGE

    a0 += __shfl_xor(a0, 32, 64);
    a1 += __shfl_xor(a1, 32, 64);
    den += __shfl_xor(den, 32, 64);

    if (es == 0) {
        float rd = __builtin_amdgcn_rcpf(den);
        float2 b = *(const float2*)(bias + fl * 2);
        float2 o;
        o.x = a0 * rd + b.x;
        o.y = a1 * rd + b.y;
        *(float2*)(out + (size_t)n * OUT_DIM + fl * 2) = o;
    }
}

// ===========================================================================
extern "C" void kernel_launch(void* const* d_in, const int* in_sizes, int n_in,
                              void* d_out, int out_size, void* d_ws, size_t ws_size,
                              hipStream_t stream) {
    const float* x      = (const float*)d_in[0];
    const int*   edges  = (const int*)d_in[1];
    const float* Wlin_h = (const float*)d_in[2];
    const float* Wseq_h = (const float*)d_in[3];
    const float* a1_h   = (const float*)d_in[4];
    const float* b1_h   = (const float*)d_in[5];
    const float* a2_h   = (const float*)d_in[6];
    const float* b2_h   = (const float*)d_in[7];
    const float* bias_h = (const float*)d_in[8];
    const float* Wlin_c = (const float*)d_in[9];
    const float* Wseq_c = (const float*)d_in[10];
    const float* a1_c   = (const float*)d_in[11];
    const float* b1_c   = (const float*)d_in[12];
    const float* a2_c   = (const float*)d_in[13];
    const float* b2_c   = (const float*)d_in[14];
    const float* bias_c = (const float*)d_in[15];

    const int N = in_sizes[0] / IN_DIM;
    const int E = in_sizes[1] / 2;
    const int* src = edges;
    const int* dst = edges + E;

    char* ws = (char*)d_ws;
    size_t off = 0;
    ushort* WC1   = (ushort*)(ws + off); off += (size_t)HF * IN_DIM * 2;
    ushort* WC2   = (ushort*)(ws + off); off += (size_t)OUT_DIM * HF * 2;
    ushort* S1    = (ushort*)(ws + off); off += (size_t)N * HF * 2;
    ushort* S2    = S1;  // S1 dead after gather1; reuse for S2 [N][64]
    ushort* HCAT  = (ushort*)(ws + off); off += (size_t)N * HF * 2;
    float*  F1    = (float*)(ws + off);  off += (size_t)N * H_NUM * 4;
    float*  F2    = (float*)(ws + off);  off += (size_t)N * H_NUM * 4;
    float*  F1c   = (float*)(ws + off);  off += (size_t)N * 4;
    float*  F2c   = (float*)(ws + off);  off += (size_t)N * 4;
    int* COUNTS   = (int*)(ws + off);    off += (size_t)N * 4;
    int* STARTS   = (int*)(ws + off);    off += ((size_t)N + 1) * 4;
    int* CURSOR   = (int*)(ws + off);    off += (size_t)N * 4;
    int* DSTS     = (int*)(ws + off);    off += (size_t)E * 4;
    int* LEXCL    = (int*)(ws + off);    off += (size_t)N * 4;
    int* PART     = (int*)(ws + off);    off += 512 * 4;

    float* out = (float*)d_out;

    const int eg = (E + 255) / 256;
    const int NB = (N + 255) / 256;

    // ---- CSR build (shared by both layers); DSTS = dst sorted by src
    hipLaunchKernelGGL(zero_i32, dim3(NB), dim3(256), 0, stream, COUNTS, N);
    hipLaunchKernelGGL(hist_kernel, dim3(eg), dim3(256), 0, stream, src, COUNTS, E);
    hipLaunchKernelGGL(scan_blk, dim3(NB), dim3(256), 0, stream, COUNTS, LEXCL, PART, N);
    hipLaunchKernelGGL(scan_part, dim3(1), dim3(256), 0, stream, PART, NB);
    hipLaunchKernelGGL(scan_add, dim3(NB), dim3(256), 0, stream, LEXCL, PART, STARTS, CURSOR, N, NB);
    hipLaunchKernelGGL(scatter_kernel, dim3(eg), dim3(256), 0, stream, src, dst, CURSOR, DSTS, E);

    // ---- fold weights, both layers (bf16 out)
    hipLaunchKernelGGL(wcomb_kernel,
                       dim3((H_NUM * F_DIM * IN_DIM + OUT_DIM * HF + 255) / 256), dim3(256),
                       0, stream, Wlin_h, Wseq_h, Wlin_c, Wseq_c, WC1, WC2);

    // ---- layer 1: S1 = x @ Wc1^T  (BM=32, XCD-paired swizzle; fused f1/f2)
    {
        int nbx = (N + 31) / 32;
        int gx = 16 * ((nbx + 7) / 8);
        hipLaunchKernelGGL((gemm_f32a<128, IN_DIM, 4>), dim3(gx), dim3(256),
                           0, stream, x, WC1, S1, N, HF,
                           a1_h, b1_h, a2_h, b2_h, F1, F2);
    }

    // ---- gather layer 1 (inline coef + normalize + bias + ELU) -> HCAT bf16
    hipLaunchKernelGGL(gather1_kernel, dim3((N + 3) / 4), dim3(256), 0, stream,
                       STARTS, DSTS, F1, F2, S1, bias_h, HCAT, N);

    // ---- classifier: S2 = hcat @ Wc2^T  (BM=64; fused f1c/f2c)
    hipLaunchKernelGGL((gemm_bf16<OUT_DIM, HF, 1>), dim3((N + 63) / 64, 1), dim3(256),
                       0, stream, HCAT, WC2, S2, N, OUT_DIM,
                       a1_c, b1_c, a2_c, b2_c, F1c, F2c);

    // ---- gather classifier (inline coef + normalize + bias) -> out fp32
    hipLaunchKernelGGL(gather2_kernel, dim3((N + 3) / 4), dim3(256), 0, stream,
                       STARTS, DSTS, F1c, F2c, S2, bias_c, out, N);
}